// Round 6
// baseline (960.437 us; speedup 1.0000x reference)
//
#include <hip/hip_runtime.h>
#include <math.h>

#define NN    16384
#define EE    262144
#define ET    (EE + NN)      // edges + self loops
#define NB    8
#define IN_F  768
#define HID1  256
#define H1    4
#define D1    (H1*HID1)      // 1024
#define OUT2  128
#define H2    2
#define D2    (H2*OUT2)      // 256

typedef __attribute__((ext_vector_type(8))) short short8;
typedef __attribute__((ext_vector_type(4))) float f32x4;

__device__ __forceinline__ unsigned short f2bf(float v) {
    unsigned u = __float_as_uint(v);
    u = (u + 0x7FFFu + ((u >> 16) & 1u)) >> 16;
    return (unsigned short)u;
}
__device__ __forceinline__ float bf2f(unsigned short b) {
    return __uint_as_float((unsigned)b << 16);
}

// ---------------- CSR build ----------------

__global__ void hist_kernel(const int* __restrict__ ei, const int* __restrict__ batch,
                            int* __restrict__ deg, int* __restrict__ n_g, int* __restrict__ e_cnt) {
    __shared__ int le[NB], ln[NB];
    int tid = threadIdx.x;
    if (tid < NB) { le[tid] = 0; ln[tid] = 0; }
    __syncthreads();
    int t = blockIdx.x * blockDim.x + tid;
    if (t < EE) {
        int s = ei[t];
        int d = ei[EE + t];
        atomicAdd(&deg[d], 1);
        atomicAdd(&le[batch[s]], 1);
    }
    if (t < NN) {
        atomicAdd(&ln[batch[t]], 1);
    }
    __syncthreads();
    if (tid < NB) {
        if (le[tid]) atomicAdd(&e_cnt[tid], le[tid]);
        if (ln[tid]) atomicAdd(&n_g[tid], ln[tid]);
    }
}

__global__ __launch_bounds__(1024) void scan_kernel(const int* __restrict__ deg, int* __restrict__ row_ptr) {
    __shared__ int sums[1024];
    int t = threadIdx.x;
    int base = t * 16;
    int local[16];
    int acc = 0;
#pragma unroll
    for (int i = 0; i < 16; i++) { local[i] = acc; acc += deg[base + i] + 1; }  // +1 = self loop
    sums[t] = acc;
    __syncthreads();
    for (int off = 1; off < 1024; off <<= 1) {
        int v = (t >= off) ? sums[t - off] : 0;
        __syncthreads();
        sums[t] += v;
        __syncthreads();
    }
    int prev = (t == 0) ? 0 : sums[t - 1];
#pragma unroll
    for (int i = 0; i < 16; i++) row_ptr[base + i] = prev + local[i];
    if (t == 1023) row_ptr[NN] = sums[1023];
}

__global__ void scatter_kernel(const int* __restrict__ ei, const int* __restrict__ row_ptr,
                               int* __restrict__ cursor, int* __restrict__ colidx) {
    int t = blockIdx.x * blockDim.x + threadIdx.x;
    if (t >= ET) return;
    int s, d;
    if (t < EE) { s = ei[t]; d = ei[EE + t]; }
    else        { s = d = t - EE; }
    int pos = row_ptr[d] + atomicAdd(&cursor[d], 1);
    colidx[pos] = s;
}

// ---------------- fp32 -> bf16 splits ----------------

__global__ void split_kernel(const float* __restrict__ in, unsigned short* __restrict__ hi,
                             unsigned short* __restrict__ lo, int n4) {
    int i = blockIdx.x * blockDim.x + threadIdx.x;
    if (i >= n4) return;
    float4 v = ((const float4*)in)[i];
    ushort4 h, l;
    h.x = f2bf(v.x); l.x = f2bf(v.x - bf2f(h.x));
    h.y = f2bf(v.y); l.y = f2bf(v.y - bf2f(h.y));
    h.z = f2bf(v.z); l.z = f2bf(v.z - bf2f(h.z));
    h.w = f2bf(v.w); l.w = f2bf(v.w - bf2f(h.w));
    ((ushort4*)hi)[i] = h;
    ((ushort4*)lo)[i] = l;
}

__global__ void tobf_kernel(const float* __restrict__ in, unsigned short* __restrict__ hi, int n4) {
    int i = blockIdx.x * blockDim.x + threadIdx.x;
    if (i >= n4) return;
    float4 v = ((const float4*)in)[i];
    ushort4 h;
    h.x = f2bf(v.x); h.y = f2bf(v.y); h.z = f2bf(v.z); h.w = f2bf(v.w);
    ((ushort4*)hi)[i] = h;
}

// ---------------- bf16 split MFMA GEMM, bf16 output ----------------
// C[M,N] = (Ahi+Alo) @ B^T ;  TERMS=2: B=Bhi ; TERMS=3: B=Bhi+Blo (hi*lo term).
// 128x128 tile, BK=32, 256 threads (2x2 waves, each 64x64 = 4x4 of 16x16x32).

__device__ __forceinline__ void ld_lds16(const unsigned short* g, unsigned short* l) {
    __builtin_amdgcn_global_load_lds((__attribute__((address_space(1))) void*)g,
                                     (__attribute__((address_space(3))) void*)l, 16, 0, 0);
}

#define BM 128
#define BN 128
#define BK 32

template <int TERMS>
__global__ __launch_bounds__(256) void gemm_mfma(const unsigned short* __restrict__ Ahi,
                                                 const unsigned short* __restrict__ Alo,
                                                 const unsigned short* __restrict__ Bhi,
                                                 const unsigned short* __restrict__ Blo,
                                                 unsigned short* __restrict__ Cb,
                                                 int M, int N, int K) {
    __shared__ __align__(16) unsigned short sA[2][BM * BK];
    __shared__ __align__(16) unsigned short sB[2][BN * BK];
    int t = threadIdx.x;
    int lane = t & 63, wave = t >> 6;
    int bm = blockIdx.y * BM, bn = blockIdx.x * BN;
    int wm = (wave & 1) * 64, wn = (wave >> 1) * 64;

    // staging role: wave 0 -> sA[0](hi), 1 -> sA[1](lo), 2 -> sB[0](hi), 3 -> sB[1](lo, TERMS=3)
    const unsigned short* gbase;
    unsigned short* lbase;
    if      (wave == 0) { gbase = Ahi + (size_t)bm * K; lbase = sA[0]; }
    else if (wave == 1) { gbase = Alo + (size_t)bm * K; lbase = sA[1]; }
    else if (wave == 2) { gbase = Bhi + (size_t)bn * K; lbase = sB[0]; }
    else                { gbase = (TERMS == 3 ? Blo : Bhi) + (size_t)bn * K; lbase = sB[1]; }
    bool do_stage = (wave < 3) || (TERMS == 3);
    const unsigned short* gsrc = gbase + (size_t)(lane >> 2) * K + (lane & 3) * 8;

    f32x4 zero = {0.f, 0.f, 0.f, 0.f};
    f32x4 acc[4][4];
#pragma unroll
    for (int i = 0; i < 4; i++)
#pragma unroll
        for (int j = 0; j < 4; j++) acc[i][j] = zero;

    int row16 = lane & 15;
    int kq = (lane >> 4) * 8;

    for (int k0 = 0; k0 < K; k0 += BK) {
        if (do_stage) {
#pragma unroll
            for (int i = 0; i < 8; i++)
                ld_lds16(gsrc + k0 + (size_t)(i * 16) * K, lbase + i * 16 * BK);
        }
        __syncthreads();

        short8 ah[4], alo[4], bh[4], blo[4];
#pragma unroll
        for (int mt = 0; mt < 4; mt++) {
            int r = (wm + mt * 16 + row16) * BK + kq;
            ah[mt]  = *(const short8*)&sA[0][r];
            alo[mt] = *(const short8*)&sA[1][r];
        }
#pragma unroll
        for (int nt = 0; nt < 4; nt++) {
            int r = (wn + nt * 16 + row16) * BK + kq;
            bh[nt]  = *(const short8*)&sB[0][r];
            if (TERMS == 3) blo[nt] = *(const short8*)&sB[1][r];
        }
#pragma unroll
        for (int mt = 0; mt < 4; mt++)
#pragma unroll
            for (int nt = 0; nt < 4; nt++) {
                acc[mt][nt] = __builtin_amdgcn_mfma_f32_16x16x32_bf16(ah[mt],  bh[nt],  acc[mt][nt], 0, 0, 0);
                acc[mt][nt] = __builtin_amdgcn_mfma_f32_16x16x32_bf16(alo[mt], bh[nt],  acc[mt][nt], 0, 0, 0);
                if (TERMS == 3)
                    acc[mt][nt] = __builtin_amdgcn_mfma_f32_16x16x32_bf16(ah[mt], blo[nt], acc[mt][nt], 0, 0, 0);
            }
        __syncthreads();
    }

    // C/D layout: col = lane&15, row = (lane>>4)*4 + reg  [m91-verified]
    int crow0 = bm + wm + (lane >> 4) * 4;
    int ccol0 = bn + wn + row16;
#pragma unroll
    for (int mt = 0; mt < 4; mt++)
#pragma unroll
        for (int nt = 0; nt < 4; nt++)
#pragma unroll
            for (int reg = 0; reg < 4; reg++)
                Cb[(size_t)(crow0 + mt * 16 + reg) * N + ccol0 + nt * 16] = f2bf(acc[mt][nt][reg]);
}

// ---------------- attention logits: al_s/al_d per (node, head) ----------------

template <int H, int CH>
__global__ void al_kernel(const unsigned short* __restrict__ h, const float* __restrict__ a_s,
                          const float* __restrict__ a_d, float* __restrict__ als,
                          float* __restrict__ ald) {
    int node = blockIdx.x;
    int wave = threadIdx.x >> 6;
    int lane = threadIdx.x & 63;
    const unsigned short* row = h + (size_t)node * (H * CH) + wave * CH;
    float ss = 0.f, sd = 0.f;
#pragma unroll
    for (int c = lane; c < CH; c += 64) {
        float v = bf2f(row[c]);
        ss += v * a_s[wave * CH + c];
        sd += v * a_d[wave * CH + c];
    }
#pragma unroll
    for (int off = 32; off; off >>= 1) {
        ss += __shfl_down(ss, off);
        sd += __shfl_down(sd, off);
    }
    if (lane == 0) {
        als[node * H + wave] = ss;
        ald[node * H + wave] = sd;
    }
}

__device__ __forceinline__ float leaky(float v) { return v > 0.f ? v : 0.2f * v; }
__device__ __forceinline__ float elu1(float v) { return v > 0.f ? v : (__expf(v) - 1.f); }

// ---------------- GAT layer 1 aggregation (4 heads x 256 ch, concat) ----------------
// block per dst node (fetch-BW-bound), writes h1 as bf16 hi/lo

__global__ __launch_bounds__(256) void agg1_kernel(const unsigned short* __restrict__ h,
                                                   const float* __restrict__ als,
                                                   const float* __restrict__ ald,
                                                   const int* __restrict__ row_ptr,
                                                   const int* __restrict__ colidx,
                                                   const float* __restrict__ bias,
                                                   unsigned short* __restrict__ out_hi,
                                                   unsigned short* __restrict__ out_lo) {
    int d = blockIdx.x;
    int t = threadIdx.x;
    int lane = t & 63, wave = t >> 6;
    int start = row_ptr[d], end = row_ptr[d + 1];

    __shared__ float ald_l[H1];
    __shared__ float wred[4][H1];
    __shared__ float sm[H1], sinv[H1];
    __shared__ int   s_src[64];
    __shared__ float s_w[64 * H1];

    if (t < H1) ald_l[t] = ald[d * H1 + t];
    __syncthreads();

    // pass 1: per-head max
    float mx[H1] = {-1e30f, -1e30f, -1e30f, -1e30f};
    for (int e = start + t; e < end; e += 256) {
        int s = colidx[e];
        const float* as = als + s * H1;
#pragma unroll
        for (int hh = 0; hh < H1; hh++)
            mx[hh] = fmaxf(mx[hh], leaky(as[hh] + ald_l[hh]));
    }
#pragma unroll
    for (int hh = 0; hh < H1; hh++)
#pragma unroll
        for (int off = 32; off; off >>= 1)
            mx[hh] = fmaxf(mx[hh], __shfl_down(mx[hh], off));
    if (lane == 0) {
#pragma unroll
        for (int hh = 0; hh < H1; hh++) wred[wave][hh] = mx[hh];
    }
    __syncthreads();
    if (t < H1) sm[t] = fmaxf(fmaxf(wred[0][t], wred[1][t]), fmaxf(wred[2][t], wred[3][t]));
    __syncthreads();

    // pass 2: denominator
    float dn[H1] = {0.f, 0.f, 0.f, 0.f};
    for (int e = start + t; e < end; e += 256) {
        int s = colidx[e];
        const float* as = als + s * H1;
#pragma unroll
        for (int hh = 0; hh < H1; hh++)
            dn[hh] += __expf(leaky(as[hh] + ald_l[hh]) - sm[hh]);
    }
#pragma unroll
    for (int hh = 0; hh < H1; hh++)
#pragma unroll
        for (int off = 32; off; off >>= 1)
            dn[hh] += __shfl_down(dn[hh], off);
    if (lane == 0) {
#pragma unroll
        for (int hh = 0; hh < H1; hh++) wred[wave][hh] = dn[hh];
    }
    __syncthreads();
    if (t < H1) sinv[t] = 1.f / (wred[0][t] + wred[1][t] + wred[2][t] + wred[3][t] + 1e-16f);
    __syncthreads();

    // pass 3: weighted accumulate, chunked
    float4 acc = make_float4(0.f, 0.f, 0.f, 0.f);
    int myh = t >> 6;
    for (int base = start; base < end; base += 64) {
        int ne = min(64, end - base);
        if (t < ne * H1) {
            int ei = t >> 2, hh = t & 3;
            int s = colidx[base + ei];
            if (hh == 0) s_src[ei] = s;
            float v = leaky(als[s * H1 + hh] + ald_l[hh]);
            s_w[(ei << 2) + hh] = __expf(v - sm[hh]) * sinv[hh];
        }
        __syncthreads();
        for (int k = 0; k < ne; k++) {
            int s = s_src[k];
            float w = s_w[(k << 2) + myh];
            ushort4 hv = *(const ushort4*)(h + (size_t)s * D1 + t * 4);
            acc.x += w * bf2f(hv.x); acc.y += w * bf2f(hv.y);
            acc.z += w * bf2f(hv.z); acc.w += w * bf2f(hv.w);
        }
        __syncthreads();
    }

    float4 bv = *(const float4*)(bias + t * 4);
    float4 o;
    o.x = elu1(acc.x + bv.x); o.y = elu1(acc.y + bv.y);
    o.z = elu1(acc.z + bv.z); o.w = elu1(acc.w + bv.w);
    ushort4 oh, ol;
    oh.x = f2bf(o.x); ol.x = f2bf(o.x - bf2f(oh.x));
    oh.y = f2bf(o.y); ol.y = f2bf(o.y - bf2f(oh.y));
    oh.z = f2bf(o.z); ol.z = f2bf(o.z - bf2f(oh.z));
    oh.w = f2bf(o.w); ol.w = f2bf(o.w - bf2f(oh.w));
    *(ushort4*)(out_hi + (size_t)d * D1 + t * 4) = oh;
    *(ushort4*)(out_lo + (size_t)d * D1 + t * 4) = ol;
}

// ---------------- GAT layer 2 aggregation (2 heads x 128 ch, mean) + pool ----------------
// Block per dst node. Pass 3 splits EDGES across the 4 waves (k = wave, wave+4, ...):
// each wave covers the full 512B row (lane -> ushort4), so the serial per-stream
// trip count is deg/4 (~4) instead of deg (~17), with 4 independent gather streams
// per node. Cross-wave partials summed once via LDS; head-mean via shfl_xor(32).

__global__ __launch_bounds__(256) void agg2_kernel(const unsigned short* __restrict__ h,
                                                   const float* __restrict__ als,
                                                   const float* __restrict__ ald,
                                                   const int* __restrict__ row_ptr,
                                                   const int* __restrict__ colidx,
                                                   const float* __restrict__ bias,
                                                   const int* __restrict__ batch,
                                                   float* __restrict__ out,
                                                   float* __restrict__ pooled) {
    int d = blockIdx.x;
    int t = threadIdx.x;
    int lane = t & 63, wave = t >> 6;
    int start = row_ptr[d], end = row_ptr[d + 1];

    __shared__ float ald_l[H2];
    __shared__ float wred[4][H2];
    __shared__ float sm[H2], sinv[H2];
    __shared__ int   s_src[64];
    __shared__ float s_w[64][H2];
    __shared__ float4 part[4][64];

    if (t < H2) ald_l[t] = ald[d * H2 + t];
    __syncthreads();

    // pass 1: per-head max
    float mx[H2] = {-1e30f, -1e30f};
    for (int e = start + t; e < end; e += 256) {
        int s = colidx[e];
        const float* as = als + s * H2;
#pragma unroll
        for (int hh = 0; hh < H2; hh++)
            mx[hh] = fmaxf(mx[hh], leaky(as[hh] + ald_l[hh]));
    }
#pragma unroll
    for (int hh = 0; hh < H2; hh++)
#pragma unroll
        for (int off = 32; off; off >>= 1)
            mx[hh] = fmaxf(mx[hh], __shfl_down(mx[hh], off));
    if (lane == 0) {
#pragma unroll
        for (int hh = 0; hh < H2; hh++) wred[wave][hh] = mx[hh];
    }
    __syncthreads();
    if (t < H2) sm[t] = fmaxf(fmaxf(wred[0][t], wred[1][t]), fmaxf(wred[2][t], wred[3][t]));
    __syncthreads();

    // pass 2: denominator
    float dn[H2] = {0.f, 0.f};
    for (int e = start + t; e < end; e += 256) {
        int s = colidx[e];
        const float* as = als + s * H2;
#pragma unroll
        for (int hh = 0; hh < H2; hh++)
            dn[hh] += __expf(leaky(as[hh] + ald_l[hh]) - sm[hh]);
    }
#pragma unroll
    for (int hh = 0; hh < H2; hh++)
#pragma unroll
        for (int off = 32; off; off >>= 1)
            dn[hh] += __shfl_down(dn[hh], off);
    if (lane == 0) {
#pragma unroll
        for (int hh = 0; hh < H2; hh++) wred[wave][hh] = dn[hh];
    }
    __syncthreads();
    if (t < H2) sinv[t] = 1.f / (wred[0][t] + wred[1][t] + wred[2][t] + wred[3][t] + 1e-16f);
    __syncthreads();

    // pass 3: edge-split across waves, channel-parallel within wave
    int myh = lane >> 5;   // lane*4 channels: <128 head0, >=128 head1
    float4 acc = make_float4(0.f, 0.f, 0.f, 0.f);
    for (int base = start; base < end; base += 64) {
        int ne = min(64, end - base);
        if (t < ne * 2) {
            int ei = t >> 1, hh = t & 1;
            int s = colidx[base + ei];
            if (hh == 0) s_src[ei] = s;
            float v = leaky(als[s * H2 + hh] + ald_l[hh]);
            s_w[ei][hh] = __expf(v - sm[hh]) * sinv[hh];
        }
        __syncthreads();
        for (int k = wave; k < ne; k += 4) {
            int s = s_src[k];
            float w = s_w[k][myh];
            ushort4 hv = *(const ushort4*)(h + (size_t)s * D2 + lane * 4);
            acc.x += w * bf2f(hv.x); acc.y += w * bf2f(hv.y);
            acc.z += w * bf2f(hv.z); acc.w += w * bf2f(hv.w);
        }
        __syncthreads();
    }
    part[wave][lane] = acc;
    __syncthreads();

    if (wave == 0) {
        float4 a0 = part[0][lane], a1 = part[1][lane];
        float4 a2 = part[2][lane], a3 = part[3][lane];
        float4 s4;
        s4.x = (a0.x + a1.x) + (a2.x + a3.x);
        s4.y = (a0.y + a1.y) + (a2.y + a3.y);
        s4.z = (a0.z + a1.z) + (a2.z + a3.z);
        s4.w = (a0.w + a1.w) + (a2.w + a3.w);
        float4 p;
        p.x = __shfl_xor(s4.x, 32); p.y = __shfl_xor(s4.y, 32);
        p.z = __shfl_xor(s4.z, 32); p.w = __shfl_xor(s4.w, 32);
        if (lane < 32) {
            int c = lane * 4;
            float4 bv = *(const float4*)(bias + c);
            float4 o;
            o.x = elu1((s4.x + p.x) * 0.5f + bv.x);
            o.y = elu1((s4.y + p.y) * 0.5f + bv.y);
            o.z = elu1((s4.z + p.z) * 0.5f + bv.z);
            o.w = elu1((s4.w + p.w) * 0.5f + bv.w);
            *(float4*)(out + (size_t)d * OUT2 + c) = o;
            float* pb = pooled + batch[d] * OUT2 + c;
            atomicAdd(pb + 0, o.x); atomicAdd(pb + 1, o.y);
            atomicAdd(pb + 2, o.z); atomicAdd(pb + 3, o.w);
        }
    }
}

// ---------------- per-graph head: proj + LN + risk MLP ----------------

__global__ __launch_bounds__(256) void final_kernel(const float* __restrict__ pooled_sum,
                                                    const int* __restrict__ n_g_i,
                                                    const int* __restrict__ e_cnt,
                                                    const float* __restrict__ projW,
                                                    const float* __restrict__ projb,
                                                    const float* __restrict__ lng,
                                                    const float* __restrict__ lnb,
                                                    const float* __restrict__ rhW1,
                                                    const float* __restrict__ rhb1,
                                                    const float* __restrict__ rhW2,
                                                    const float* __restrict__ rhb2,
                                                    float* __restrict__ out_se,
                                                    float* __restrict__ out_risk) {
    int b = blockIdx.x;
    int t = threadIdx.x;
    __shared__ float pooled[OUT2];
    __shared__ float pe[768];
    __shared__ float red[256];
    __shared__ float hid[32];
    __shared__ float stat_mu, stat_inv;

    float ng = (float)n_g_i[b];
    if (t < OUT2) pooled[t] = pooled_sum[b * OUT2 + t] / fmaxf(ng, 1.0f);
    __syncthreads();

    for (int j = t; j < 768; j += 256) {
        const float* wr = projW + (size_t)j * OUT2;
        float s = projb[j];
        for (int c = 0; c < OUT2; c++) s += pooled[c] * wr[c];
        pe[j] = s;
    }
    __syncthreads();

    float ls = 0.f, lq = 0.f;
    for (int j = t; j < 768; j += 256) { float v = pe[j]; ls += v; lq += v * v; }
    red[t] = ls;
    __syncthreads();
    for (int off = 128; off; off >>= 1) { if (t < off) red[t] += red[t + off]; __syncthreads(); }
    float tot = red[0];
    __syncthreads();
    red[t] = lq;
    __syncthreads();
    for (int off = 128; off; off >>= 1) { if (t < off) red[t] += red[t + off]; __syncthreads(); }
    float totq = red[0];
    if (t == 0) {
        float mu = tot / 768.f;
        float var = totq / 768.f - mu * mu;
        stat_mu = mu;
        stat_inv = 1.f / sqrtf(var + 1e-5f);
    }
    __syncthreads();
    float mu = stat_mu, inv = stat_inv;
    for (int j = t; j < 768; j += 256)
        out_se[(size_t)b * 768 + j] = (pe[j] - mu) * inv * lng[j] + lnb[j];

    float s0 = (float)e_cnt[b] / (ng + 1e-6f);
    float s1 = logf(ng + 1.0f);
    if (t < 32) {
        const float* wr = rhW1 + t * (OUT2 + 2);
        float s = rhb1[t];
        for (int c = 0; c < OUT2; c++) s += pooled[c] * wr[c];
        s += s0 * wr[OUT2] + s1 * wr[OUT2 + 1];
        hid[t] = fmaxf(s, 0.f);
    }
    __syncthreads();
    if (t == 0) {
        float s = rhb2[0];
        for (int k = 0; k < 32; k++) s += hid[k] * rhW2[k];
        out_risk[b] = 1.f / (1.f + __expf(-s));
    }
}

// ---------------- launch ----------------

extern "C" void kernel_launch(void* const* d_in, const int* in_sizes, int n_in,
                              void* d_out, int out_size, void* d_ws, size_t ws_size,
                              hipStream_t stream) {
    const float* x     = (const float*)d_in[0];
    const int*   ei    = (const int*)  d_in[1];
    const int*   batch = (const int*)  d_in[2];
    const float* W1    = (const float*)d_in[3];
    const float* a_s1  = (const float*)d_in[4];
    const float* a_d1  = (const float*)d_in[5];
    const float* b1    = (const float*)d_in[6];
    const float* W2    = (const float*)d_in[7];
    const float* a_s2  = (const float*)d_in[8];
    const float* a_d2  = (const float*)d_in[9];
    const float* b2    = (const float*)d_in[10];
    const float* projW = (const float*)d_in[11];
    const float* projb = (const float*)d_in[12];
    const float* lng   = (const float*)d_in[13];
    const float* lnb   = (const float*)d_in[14];
    const float* rhW1  = (const float*)d_in[15];
    const float* rhb1  = (const float*)d_in[16];
    const float* rhW2  = (const float*)d_in[17];
    const float* rhb2  = (const float*)d_in[18];

    char* ws = (char*)d_ws;
    size_t off = 0;
    auto alloc = [&](size_t bytes) -> void* {
        void* p = ws + off;
        off += (bytes + 255) & ~(size_t)255;
        return p;
    };

    // regionA: x hi/lo (2 x 24MB) before gemm1; reused as h1 hi/lo (2 x 33.5MB) after agg1
    unsigned short* regionA = (unsigned short*)alloc((size_t)2 * NN * D1 * 2);
    unsigned short* x_hi = regionA;
    unsigned short* x_lo = regionA + (size_t)NN * IN_F;
    unsigned short* h1hi = regionA;
    unsigned short* h1lo = regionA + (size_t)NN * D1;

    unsigned short* h1bf = (unsigned short*)alloc((size_t)NN * D1 * 2);  // gemm1 out (bf16)
    unsigned short* h2bf = (unsigned short*)alloc((size_t)NN * D2 * 2);  // gemm2 out (bf16)
    unsigned short* W1hi = (unsigned short*)alloc((size_t)D1 * IN_F * 2);
    unsigned short* W2hi = (unsigned short*)alloc((size_t)D2 * D1 * 2);
    unsigned short* W2lo = (unsigned short*)alloc((size_t)D2 * D1 * 2);
    float* als1   = (float*)alloc((size_t)NN * H1 * 4);
    float* ald1   = (float*)alloc((size_t)NN * H1 * 4);
    float* als2   = (float*)alloc((size_t)NN * H2 * 4);
    float* ald2   = (float*)alloc((size_t)NN * H2 * 4);
    int*   row_ptr= (int*)  alloc((size_t)(NN + 1) * 4);
    int*   colidx = (int*)  alloc((size_t)ET * 4);
    // zeroed region (one memset)
    size_t zoff = off;
    int*   deg    = (int*)  alloc((size_t)NN * 4);
    int*   cursor = (int*)  alloc((size_t)NN * 4);
    int*   n_g    = (int*)  alloc((size_t)NB * 4);
    int*   e_cnt  = (int*)  alloc((size_t)NB * 4);
    float* pooled = (float*)alloc((size_t)NB * OUT2 * 4);
    size_t zbytes = off - zoff;

    float* out_se   = (float*)d_out;
    float* h2out    = out_se + NB * 768;
    float* out_risk = h2out + (size_t)NN * OUT2;

    hipMemsetAsync(ws + zoff, 0, zbytes, stream);

    hist_kernel<<<(EE + 255) / 256, 256, 0, stream>>>(ei, batch, deg, n_g, e_cnt);
    scan_kernel<<<1, 1024, 0, stream>>>(deg, row_ptr);
    scatter_kernel<<<(ET + 255) / 256, 256, 0, stream>>>(ei, row_ptr, cursor, colidx);

    // bf16 splits
    split_kernel<<<((NN * IN_F / 4) + 255) / 256, 256, 0, stream>>>(x, x_hi, x_lo, NN * IN_F / 4);
    tobf_kernel<<<((D1 * IN_F / 4) + 255) / 256, 256, 0, stream>>>(W1, W1hi, D1 * IN_F / 4);
    split_kernel<<<((D2 * D1 / 4) + 255) / 256, 256, 0, stream>>>(W2, W2hi, W2lo, D2 * D1 / 4);

    // layer 1 (2-term: x compensated, W1 plain bf16)
    gemm_mfma<2><<<dim3(D1 / BN, NN / BM), 256, 0, stream>>>(x_hi, x_lo, W1hi, W1hi, h1bf, NN, D1, IN_F);
    al_kernel<H1, HID1><<<NN, H1 * 64, 0, stream>>>(h1bf, a_s1, a_d1, als1, ald1);
    agg1_kernel<<<NN, 256, 0, stream>>>(h1bf, als1, ald1, row_ptr, colidx, b1, h1hi, h1lo);

    // layer 2 (3-term)
    gemm_mfma<3><<<dim3(D2 / BN, NN / BM), 256, 0, stream>>>(h1hi, h1lo, W2hi, W2lo, h2bf, NN, D2, D1);
    al_kernel<H2, OUT2><<<NN, H2 * 64, 0, stream>>>(h2bf, a_s2, a_d2, als2, ald2);
    agg2_kernel<<<NN, 256, 0, stream>>>(h2bf, als2, ald2, row_ptr, colidx, b2, batch, h2out, pooled);

    // per-graph head
    final_kernel<<<NB, 256, 0, stream>>>(pooled, n_g, e_cnt, projW, projb, lng, lnb,
                                         rhW1, rhb1, rhW2, rhb2, out_se, out_risk);
}

// Round 7
// 579.031 us; speedup vs baseline: 1.6587x; 1.6587x over previous
//
#include <hip/hip_runtime.h>
#include <math.h>

#define NN    16384
#define EE    262144
#define ET    (EE + NN)      // edges + self loops
#define NB    8
#define IN_F  768
#define HID1  256
#define H1    4
#define D1    (H1*HID1)      // 1024
#define OUT2  128
#define H2    2
#define D2    (H2*OUT2)      // 256

typedef __attribute__((ext_vector_type(8))) short short8;
typedef __attribute__((ext_vector_type(4))) float f32x4;

__device__ __forceinline__ unsigned short f2bf(float v) {
    unsigned u = __float_as_uint(v);
    u = (u + 0x7FFFu + ((u >> 16) & 1u)) >> 16;
    return (unsigned short)u;
}
__device__ __forceinline__ float bf2f(unsigned short b) {
    return __uint_as_float((unsigned)b << 16);
}

// ---------------- CSR build ----------------

__global__ void hist_kernel(const int* __restrict__ ei, const int* __restrict__ batch,
                            int* __restrict__ deg, int* __restrict__ n_g, int* __restrict__ e_cnt) {
    __shared__ int le[NB], ln[NB];
    int tid = threadIdx.x;
    if (tid < NB) { le[tid] = 0; ln[tid] = 0; }
    __syncthreads();
    int t = blockIdx.x * blockDim.x + tid;
    if (t < EE) {
        int s = ei[t];
        int d = ei[EE + t];
        atomicAdd(&deg[d], 1);
        atomicAdd(&le[batch[s]], 1);
    }
    if (t < NN) {
        atomicAdd(&ln[batch[t]], 1);
    }
    __syncthreads();
    if (tid < NB) {
        if (le[tid]) atomicAdd(&e_cnt[tid], le[tid]);
        if (ln[tid]) atomicAdd(&n_g[tid], ln[tid]);
    }
}

__global__ __launch_bounds__(1024) void scan_kernel(const int* __restrict__ deg, int* __restrict__ row_ptr) {
    __shared__ int sums[1024];
    int t = threadIdx.x;
    int base = t * 16;
    int local[16];
    int acc = 0;
#pragma unroll
    for (int i = 0; i < 16; i++) { local[i] = acc; acc += deg[base + i] + 1; }  // +1 = self loop
    sums[t] = acc;
    __syncthreads();
    for (int off = 1; off < 1024; off <<= 1) {
        int v = (t >= off) ? sums[t - off] : 0;
        __syncthreads();
        sums[t] += v;
        __syncthreads();
    }
    int prev = (t == 0) ? 0 : sums[t - 1];
#pragma unroll
    for (int i = 0; i < 16; i++) row_ptr[base + i] = prev + local[i];
    if (t == 1023) row_ptr[NN] = sums[1023];
}

__global__ void scatter_kernel(const int* __restrict__ ei, const int* __restrict__ row_ptr,
                               int* __restrict__ cursor, int* __restrict__ colidx) {
    int t = blockIdx.x * blockDim.x + threadIdx.x;
    if (t >= ET) return;
    int s, d;
    if (t < EE) { s = ei[t]; d = ei[EE + t]; }
    else        { s = d = t - EE; }
    int pos = row_ptr[d] + atomicAdd(&cursor[d], 1);
    colidx[pos] = s;
}

// ---------------- fp32 -> bf16 splits ----------------

__global__ void split_kernel(const float* __restrict__ in, unsigned short* __restrict__ hi,
                             unsigned short* __restrict__ lo, int n4) {
    int i = blockIdx.x * blockDim.x + threadIdx.x;
    if (i >= n4) return;
    float4 v = ((const float4*)in)[i];
    ushort4 h, l;
    h.x = f2bf(v.x); l.x = f2bf(v.x - bf2f(h.x));
    h.y = f2bf(v.y); l.y = f2bf(v.y - bf2f(h.y));
    h.z = f2bf(v.z); l.z = f2bf(v.z - bf2f(h.z));
    h.w = f2bf(v.w); l.w = f2bf(v.w - bf2f(h.w));
    ((ushort4*)hi)[i] = h;
    ((ushort4*)lo)[i] = l;
}

__global__ void tobf_kernel(const float* __restrict__ in, unsigned short* __restrict__ hi, int n4) {
    int i = blockIdx.x * blockDim.x + threadIdx.x;
    if (i >= n4) return;
    float4 v = ((const float4*)in)[i];
    ushort4 h;
    h.x = f2bf(v.x); h.y = f2bf(v.y); h.z = f2bf(v.z); h.w = f2bf(v.w);
    ((ushort4*)hi)[i] = h;
}

// ---------------- bf16 split MFMA GEMM, bf16 output ----------------

__device__ __forceinline__ void ld_lds16(const unsigned short* g, unsigned short* l) {
    __builtin_amdgcn_global_load_lds((__attribute__((address_space(1))) void*)g,
                                     (__attribute__((address_space(3))) void*)l, 16, 0, 0);
}

#define BM 128
#define BN 128
#define BK 32

template <int TERMS>
__global__ __launch_bounds__(256) void gemm_mfma(const unsigned short* __restrict__ Ahi,
                                                 const unsigned short* __restrict__ Alo,
                                                 const unsigned short* __restrict__ Bhi,
                                                 const unsigned short* __restrict__ Blo,
                                                 unsigned short* __restrict__ Cb,
                                                 int M, int N, int K) {
    __shared__ __align__(16) unsigned short sA[2][BM * BK];
    __shared__ __align__(16) unsigned short sB[2][BN * BK];
    int t = threadIdx.x;
    int lane = t & 63, wave = t >> 6;
    int bm = blockIdx.y * BM, bn = blockIdx.x * BN;
    int wm = (wave & 1) * 64, wn = (wave >> 1) * 64;

    const unsigned short* gbase;
    unsigned short* lbase;
    if      (wave == 0) { gbase = Ahi + (size_t)bm * K; lbase = sA[0]; }
    else if (wave == 1) { gbase = Alo + (size_t)bm * K; lbase = sA[1]; }
    else if (wave == 2) { gbase = Bhi + (size_t)bn * K; lbase = sB[0]; }
    else                { gbase = (TERMS == 3 ? Blo : Bhi) + (size_t)bn * K; lbase = sB[1]; }
    bool do_stage = (wave < 3) || (TERMS == 3);
    const unsigned short* gsrc = gbase + (size_t)(lane >> 2) * K + (lane & 3) * 8;

    f32x4 zero = {0.f, 0.f, 0.f, 0.f};
    f32x4 acc[4][4];
#pragma unroll
    for (int i = 0; i < 4; i++)
#pragma unroll
        for (int j = 0; j < 4; j++) acc[i][j] = zero;

    int row16 = lane & 15;
    int kq = (lane >> 4) * 8;

    for (int k0 = 0; k0 < K; k0 += BK) {
        if (do_stage) {
#pragma unroll
            for (int i = 0; i < 8; i++)
                ld_lds16(gsrc + k0 + (size_t)(i * 16) * K, lbase + i * 16 * BK);
        }
        __syncthreads();

        short8 ah[4], alo[4], bh[4], blo[4];
#pragma unroll
        for (int mt = 0; mt < 4; mt++) {
            int r = (wm + mt * 16 + row16) * BK + kq;
            ah[mt]  = *(const short8*)&sA[0][r];
            alo[mt] = *(const short8*)&sA[1][r];
        }
#pragma unroll
        for (int nt = 0; nt < 4; nt++) {
            int r = (wn + nt * 16 + row16) * BK + kq;
            bh[nt]  = *(const short8*)&sB[0][r];
            if (TERMS == 3) blo[nt] = *(const short8*)&sB[1][r];
        }
#pragma unroll
        for (int mt = 0; mt < 4; mt++)
#pragma unroll
            for (int nt = 0; nt < 4; nt++) {
                acc[mt][nt] = __builtin_amdgcn_mfma_f32_16x16x32_bf16(ah[mt],  bh[nt],  acc[mt][nt], 0, 0, 0);
                acc[mt][nt] = __builtin_amdgcn_mfma_f32_16x16x32_bf16(alo[mt], bh[nt],  acc[mt][nt], 0, 0, 0);
                if (TERMS == 3)
                    acc[mt][nt] = __builtin_amdgcn_mfma_f32_16x16x32_bf16(ah[mt], blo[nt], acc[mt][nt], 0, 0, 0);
            }
        __syncthreads();
    }

    int crow0 = bm + wm + (lane >> 4) * 4;
    int ccol0 = bn + wn + row16;
#pragma unroll
    for (int mt = 0; mt < 4; mt++)
#pragma unroll
        for (int nt = 0; nt < 4; nt++)
#pragma unroll
            for (int reg = 0; reg < 4; reg++)
                Cb[(size_t)(crow0 + mt * 16 + reg) * N + ccol0 + nt * 16] = f2bf(acc[mt][nt][reg]);
}

// ---------------- attention logits ----------------

template <int H, int CH>
__global__ void al_kernel(const unsigned short* __restrict__ h, const float* __restrict__ a_s,
                          const float* __restrict__ a_d, float* __restrict__ als,
                          float* __restrict__ ald) {
    int node = blockIdx.x;
    int wave = threadIdx.x >> 6;
    int lane = threadIdx.x & 63;
    const unsigned short* row = h + (size_t)node * (H * CH) + wave * CH;
    float ss = 0.f, sd = 0.f;
#pragma unroll
    for (int c = lane; c < CH; c += 64) {
        float v = bf2f(row[c]);
        ss += v * a_s[wave * CH + c];
        sd += v * a_d[wave * CH + c];
    }
#pragma unroll
    for (int off = 32; off; off >>= 1) {
        ss += __shfl_down(ss, off);
        sd += __shfl_down(sd, off);
    }
    if (lane == 0) {
        als[node * H + wave] = ss;
        ald[node * H + wave] = sd;
    }
}

__device__ __forceinline__ float leaky(float v) { return v > 0.f ? v : 0.2f * v; }
__device__ __forceinline__ float elu1(float v) { return v > 0.f ? v : (__expf(v) - 1.f); }

// ---------------- GAT layer 1 aggregation (R4 structure + unroll-2 gather) ----------------

__global__ __launch_bounds__(256) void agg1_kernel(const unsigned short* __restrict__ h,
                                                   const float* __restrict__ als,
                                                   const float* __restrict__ ald,
                                                   const int* __restrict__ row_ptr,
                                                   const int* __restrict__ colidx,
                                                   const float* __restrict__ bias,
                                                   unsigned short* __restrict__ out_hi,
                                                   unsigned short* __restrict__ out_lo) {
    int d = blockIdx.x;
    int t = threadIdx.x;
    int lane = t & 63, wave = t >> 6;
    int start = row_ptr[d], end = row_ptr[d + 1];

    __shared__ float ald_l[H1];
    __shared__ float wred[4][H1];
    __shared__ float sm[H1], sinv[H1];
    __shared__ int   s_src[64];
    __shared__ float s_w[64 * H1];

    if (t < H1) ald_l[t] = ald[d * H1 + t];
    __syncthreads();

    float mx[H1] = {-1e30f, -1e30f, -1e30f, -1e30f};
    for (int e = start + t; e < end; e += 256) {
        int s = colidx[e];
        const float* as = als + s * H1;
#pragma unroll
        for (int hh = 0; hh < H1; hh++)
            mx[hh] = fmaxf(mx[hh], leaky(as[hh] + ald_l[hh]));
    }
#pragma unroll
    for (int hh = 0; hh < H1; hh++)
#pragma unroll
        for (int off = 32; off; off >>= 1)
            mx[hh] = fmaxf(mx[hh], __shfl_down(mx[hh], off));
    if (lane == 0) {
#pragma unroll
        for (int hh = 0; hh < H1; hh++) wred[wave][hh] = mx[hh];
    }
    __syncthreads();
    if (t < H1) sm[t] = fmaxf(fmaxf(wred[0][t], wred[1][t]), fmaxf(wred[2][t], wred[3][t]));
    __syncthreads();

    float dn[H1] = {0.f, 0.f, 0.f, 0.f};
    for (int e = start + t; e < end; e += 256) {
        int s = colidx[e];
        const float* as = als + s * H1;
#pragma unroll
        for (int hh = 0; hh < H1; hh++)
            dn[hh] += __expf(leaky(as[hh] + ald_l[hh]) - sm[hh]);
    }
#pragma unroll
    for (int hh = 0; hh < H1; hh++)
#pragma unroll
        for (int off = 32; off; off >>= 1)
            dn[hh] += __shfl_down(dn[hh], off);
    if (lane == 0) {
#pragma unroll
        for (int hh = 0; hh < H1; hh++) wred[wave][hh] = dn[hh];
    }
    __syncthreads();
    if (t < H1) sinv[t] = 1.f / (wred[0][t] + wred[1][t] + wred[2][t] + wred[3][t] + 1e-16f);
    __syncthreads();

    // pass 3: weighted accumulate, chunked; k-loop unrolled x2 (independent loads)
    float4 acc0 = make_float4(0.f, 0.f, 0.f, 0.f);
    float4 acc1 = make_float4(0.f, 0.f, 0.f, 0.f);
    int myh = t >> 6;
    for (int base = start; base < end; base += 64) {
        int ne = min(64, end - base);
        if (t < ne * H1) {
            int ei = t >> 2, hh = t & 3;
            int s = colidx[base + ei];
            if (hh == 0) s_src[ei] = s;
            float v = leaky(als[s * H1 + hh] + ald_l[hh]);
            s_w[(ei << 2) + hh] = __expf(v - sm[hh]) * sinv[hh];
        }
        __syncthreads();
        int k = 0;
        for (; k + 1 < ne; k += 2) {
            int s0 = s_src[k], s1 = s_src[k + 1];
            float w0 = s_w[(k << 2) + myh], w1 = s_w[((k + 1) << 2) + myh];
            ushort4 h0 = *(const ushort4*)(h + (size_t)s0 * D1 + t * 4);
            ushort4 h1 = *(const ushort4*)(h + (size_t)s1 * D1 + t * 4);
            acc0.x += w0 * bf2f(h0.x); acc0.y += w0 * bf2f(h0.y);
            acc0.z += w0 * bf2f(h0.z); acc0.w += w0 * bf2f(h0.w);
            acc1.x += w1 * bf2f(h1.x); acc1.y += w1 * bf2f(h1.y);
            acc1.z += w1 * bf2f(h1.z); acc1.w += w1 * bf2f(h1.w);
        }
        if (k < ne) {
            int s0 = s_src[k];
            float w0 = s_w[(k << 2) + myh];
            ushort4 h0 = *(const ushort4*)(h + (size_t)s0 * D1 + t * 4);
            acc0.x += w0 * bf2f(h0.x); acc0.y += w0 * bf2f(h0.y);
            acc0.z += w0 * bf2f(h0.z); acc0.w += w0 * bf2f(h0.w);
        }
        __syncthreads();
    }
    float4 acc;
    acc.x = acc0.x + acc1.x; acc.y = acc0.y + acc1.y;
    acc.z = acc0.z + acc1.z; acc.w = acc0.w + acc1.w;

    float4 bv = *(const float4*)(bias + t * 4);
    float4 o;
    o.x = elu1(acc.x + bv.x); o.y = elu1(acc.y + bv.y);
    o.z = elu1(acc.z + bv.z); o.w = elu1(acc.w + bv.w);
    ushort4 oh, ol;
    oh.x = f2bf(o.x); ol.x = f2bf(o.x - bf2f(oh.x));
    oh.y = f2bf(o.y); ol.y = f2bf(o.y - bf2f(oh.y));
    oh.z = f2bf(o.z); ol.z = f2bf(o.z - bf2f(oh.z));
    oh.w = f2bf(o.w); ol.w = f2bf(o.w - bf2f(oh.w));
    *(ushort4*)(out_hi + (size_t)d * D1 + t * 4) = oh;
    *(ushort4*)(out_lo + (size_t)d * D1 + t * 4) = ol;
}

// ---------------- GAT layer 2 aggregation: R4-exact structure + unroll-4 gather ----------------
// Block per dst node, thread t owns channel t (scalar 2B coalesced loads — the
// measured-good pattern, 174us). The ONLY change vs R4: the serial k-loop pays
// one lgkmcnt+vmcnt stall per 4 edges (4 independent accumulators) not per edge.

__global__ __launch_bounds__(256) void agg2_kernel(const unsigned short* __restrict__ h,
                                                   const float* __restrict__ als,
                                                   const float* __restrict__ ald,
                                                   const int* __restrict__ row_ptr,
                                                   const int* __restrict__ colidx,
                                                   const float* __restrict__ bias,
                                                   const int* __restrict__ batch,
                                                   float* __restrict__ out,
                                                   float* __restrict__ pooled) {
    int d = blockIdx.x;
    int t = threadIdx.x;
    int lane = t & 63, wave = t >> 6;
    int start = row_ptr[d], end = row_ptr[d + 1];

    __shared__ float ald_l[H2];
    __shared__ float wred[4][H2];
    __shared__ float sm[H2], sinv[H2];
    __shared__ int   s_src[128];
    __shared__ float s_w[128 * H2];
    __shared__ float red[256];

    if (t < H2) ald_l[t] = ald[d * H2 + t];
    __syncthreads();

    float mx[H2] = {-1e30f, -1e30f};
    for (int e = start + t; e < end; e += 256) {
        int s = colidx[e];
        const float* as = als + s * H2;
#pragma unroll
        for (int hh = 0; hh < H2; hh++)
            mx[hh] = fmaxf(mx[hh], leaky(as[hh] + ald_l[hh]));
    }
#pragma unroll
    for (int hh = 0; hh < H2; hh++)
#pragma unroll
        for (int off = 32; off; off >>= 1)
            mx[hh] = fmaxf(mx[hh], __shfl_down(mx[hh], off));
    if (lane == 0) {
#pragma unroll
        for (int hh = 0; hh < H2; hh++) wred[wave][hh] = mx[hh];
    }
    __syncthreads();
    if (t < H2) sm[t] = fmaxf(fmaxf(wred[0][t], wred[1][t]), fmaxf(wred[2][t], wred[3][t]));
    __syncthreads();

    float dn[H2] = {0.f, 0.f};
    for (int e = start + t; e < end; e += 256) {
        int s = colidx[e];
        const float* as = als + s * H2;
#pragma unroll
        for (int hh = 0; hh < H2; hh++)
            dn[hh] += __expf(leaky(as[hh] + ald_l[hh]) - sm[hh]);
    }
#pragma unroll
    for (int hh = 0; hh < H2; hh++)
#pragma unroll
        for (int off = 32; off; off >>= 1)
            dn[hh] += __shfl_down(dn[hh], off);
    if (lane == 0) {
#pragma unroll
        for (int hh = 0; hh < H2; hh++) wred[wave][hh] = dn[hh];
    }
    __syncthreads();
    if (t < H2) sinv[t] = 1.f / (wred[0][t] + wred[1][t] + wred[2][t] + wred[3][t] + 1e-16f);
    __syncthreads();

    // pass 3: k-loop unrolled x4 with independent accumulators
    float a0 = 0.f, a1 = 0.f, a2 = 0.f, a3 = 0.f;
    int myh = t >> 7;
    for (int base = start; base < end; base += 128) {
        int ne = min(128, end - base);
        if (t < ne * 2) {
            int ei = t >> 1, hh = t & 1;
            int s = colidx[base + ei];
            if (hh == 0) s_src[ei] = s;
            float v = leaky(als[s * H2 + hh] + ald_l[hh]);
            s_w[(ei << 1) + hh] = __expf(v - sm[hh]) * sinv[hh];
        }
        __syncthreads();
        int k = 0;
        for (; k + 3 < ne; k += 4) {
            int s0 = s_src[k],     s1 = s_src[k + 1];
            int s2 = s_src[k + 2], s3 = s_src[k + 3];
            float w0 = s_w[(k << 1) + myh],       w1 = s_w[((k + 1) << 1) + myh];
            float w2 = s_w[((k + 2) << 1) + myh], w3 = s_w[((k + 3) << 1) + myh];
            unsigned short v0 = h[(size_t)s0 * D2 + t];
            unsigned short v1 = h[(size_t)s1 * D2 + t];
            unsigned short v2 = h[(size_t)s2 * D2 + t];
            unsigned short v3 = h[(size_t)s3 * D2 + t];
            a0 += w0 * bf2f(v0); a1 += w1 * bf2f(v1);
            a2 += w2 * bf2f(v2); a3 += w3 * bf2f(v3);
        }
        for (; k < ne; k++) {
            a0 += s_w[(k << 1) + myh] * bf2f(h[(size_t)s_src[k] * D2 + t]);
        }
        __syncthreads();
    }
    red[t] = (a0 + a1) + (a2 + a3);
    __syncthreads();
    if (t < 128) {
        float v = (red[t] + red[t + 128]) * 0.5f + bias[t];
        v = elu1(v);
        out[(size_t)d * OUT2 + t] = v;
        atomicAdd(&pooled[batch[d] * OUT2 + t], v);
    }
}

// ---------------- per-graph head: proj + LN + risk MLP ----------------

__global__ __launch_bounds__(256) void final_kernel(const float* __restrict__ pooled_sum,
                                                    const int* __restrict__ n_g_i,
                                                    const int* __restrict__ e_cnt,
                                                    const float* __restrict__ projW,
                                                    const float* __restrict__ projb,
                                                    const float* __restrict__ lng,
                                                    const float* __restrict__ lnb,
                                                    const float* __restrict__ rhW1,
                                                    const float* __restrict__ rhb1,
                                                    const float* __restrict__ rhW2,
                                                    const float* __restrict__ rhb2,
                                                    float* __restrict__ out_se,
                                                    float* __restrict__ out_risk) {
    int b = blockIdx.x;
    int t = threadIdx.x;
    __shared__ float pooled[OUT2];
    __shared__ float pe[768];
    __shared__ float red[256];
    __shared__ float hid[32];
    __shared__ float stat_mu, stat_inv;

    float ng = (float)n_g_i[b];
    if (t < OUT2) pooled[t] = pooled_sum[b * OUT2 + t] / fmaxf(ng, 1.0f);
    __syncthreads();

    for (int j = t; j < 768; j += 256) {
        const float* wr = projW + (size_t)j * OUT2;
        float s = projb[j];
        for (int c = 0; c < OUT2; c++) s += pooled[c] * wr[c];
        pe[j] = s;
    }
    __syncthreads();

    float ls = 0.f, lq = 0.f;
    for (int j = t; j < 768; j += 256) { float v = pe[j]; ls += v; lq += v * v; }
    red[t] = ls;
    __syncthreads();
    for (int off = 128; off; off >>= 1) { if (t < off) red[t] += red[t + off]; __syncthreads(); }
    float tot = red[0];
    __syncthreads();
    red[t] = lq;
    __syncthreads();
    for (int off = 128; off; off >>= 1) { if (t < off) red[t] += red[t + off]; __syncthreads(); }
    float totq = red[0];
    if (t == 0) {
        float mu = tot / 768.f;
        float var = totq / 768.f - mu * mu;
        stat_mu = mu;
        stat_inv = 1.f / sqrtf(var + 1e-5f);
    }
    __syncthreads();
    float mu = stat_mu, inv = stat_inv;
    for (int j = t; j < 768; j += 256)
        out_se[(size_t)b * 768 + j] = (pe[j] - mu) * inv * lng[j] + lnb[j];

    float s0 = (float)e_cnt[b] / (ng + 1e-6f);
    float s1 = logf(ng + 1.0f);
    if (t < 32) {
        const float* wr = rhW1 + t * (OUT2 + 2);
        float s = rhb1[t];
        for (int c = 0; c < OUT2; c++) s += pooled[c] * wr[c];
        s += s0 * wr[OUT2] + s1 * wr[OUT2 + 1];
        hid[t] = fmaxf(s, 0.f);
    }
    __syncthreads();
    if (t == 0) {
        float s = rhb2[0];
        for (int k = 0; k < 32; k++) s += hid[k] * rhW2[k];
        out_risk[b] = 1.f / (1.f + __expf(-s));
    }
}

// ---------------- launch ----------------

extern "C" void kernel_launch(void* const* d_in, const int* in_sizes, int n_in,
                              void* d_out, int out_size, void* d_ws, size_t ws_size,
                              hipStream_t stream) {
    const float* x     = (const float*)d_in[0];
    const int*   ei    = (const int*)  d_in[1];
    const int*   batch = (const int*)  d_in[2];
    const float* W1    = (const float*)d_in[3];
    const float* a_s1  = (const float*)d_in[4];
    const float* a_d1  = (const float*)d_in[5];
    const float* b1    = (const float*)d_in[6];
    const float* W2    = (const float*)d_in[7];
    const float* a_s2  = (const float*)d_in[8];
    const float* a_d2  = (const float*)d_in[9];
    const float* b2    = (const float*)d_in[10];
    const float* projW = (const float*)d_in[11];
    const float* projb = (const float*)d_in[12];
    const float* lng   = (const float*)d_in[13];
    const float* lnb   = (const float*)d_in[14];
    const float* rhW1  = (const float*)d_in[15];
    const float* rhb1  = (const float*)d_in[16];
    const float* rhW2  = (const float*)d_in[17];
    const float* rhb2  = (const float*)d_in[18];

    char* ws = (char*)d_ws;
    size_t off = 0;
    auto alloc = [&](size_t bytes) -> void* {
        void* p = ws + off;
        off += (bytes + 255) & ~(size_t)255;
        return p;
    };

    unsigned short* regionA = (unsigned short*)alloc((size_t)2 * NN * D1 * 2);
    unsigned short* x_hi = regionA;
    unsigned short* x_lo = regionA + (size_t)NN * IN_F;
    unsigned short* h1hi = regionA;
    unsigned short* h1lo = regionA + (size_t)NN * D1;

    unsigned short* h1bf = (unsigned short*)alloc((size_t)NN * D1 * 2);
    unsigned short* h2bf = (unsigned short*)alloc((size_t)NN * D2 * 2);
    unsigned short* W1hi = (unsigned short*)alloc((size_t)D1 * IN_F * 2);
    unsigned short* W2hi = (unsigned short*)alloc((size_t)D2 * D1 * 2);
    unsigned short* W2lo = (unsigned short*)alloc((size_t)D2 * D1 * 2);
    float* als1   = (float*)alloc((size_t)NN * H1 * 4);
    float* ald1   = (float*)alloc((size_t)NN * H1 * 4);
    float* als2   = (float*)alloc((size_t)NN * H2 * 4);
    float* ald2   = (float*)alloc((size_t)NN * H2 * 4);
    int*   row_ptr= (int*)  alloc((size_t)(NN + 1) * 4);
    int*   colidx = (int*)  alloc((size_t)ET * 4);
    size_t zoff = off;
    int*   deg    = (int*)  alloc((size_t)NN * 4);
    int*   cursor = (int*)  alloc((size_t)NN * 4);
    int*   n_g    = (int*)  alloc((size_t)NB * 4);
    int*   e_cnt  = (int*)  alloc((size_t)NB * 4);
    float* pooled = (float*)alloc((size_t)NB * OUT2 * 4);
    size_t zbytes = off - zoff;

    float* out_se   = (float*)d_out;
    float* h2out    = out_se + NB * 768;
    float* out_risk = h2out + (size_t)NN * OUT2;

    hipMemsetAsync(ws + zoff, 0, zbytes, stream);

    hist_kernel<<<(EE + 255) / 256, 256, 0, stream>>>(ei, batch, deg, n_g, e_cnt);
    scan_kernel<<<1, 1024, 0, stream>>>(deg, row_ptr);
    scatter_kernel<<<(ET + 255) / 256, 256, 0, stream>>>(ei, row_ptr, cursor, colidx);

    split_kernel<<<((NN * IN_F / 4) + 255) / 256, 256, 0, stream>>>(x, x_hi, x_lo, NN * IN_F / 4);
    tobf_kernel<<<((D1 * IN_F / 4) + 255) / 256, 256, 0, stream>>>(W1, W1hi, D1 * IN_F / 4);
    split_kernel<<<((D2 * D1 / 4) + 255) / 256, 256, 0, stream>>>(W2, W2hi, W2lo, D2 * D1 / 4);

    gemm_mfma<2><<<dim3(D1 / BN, NN / BM), 256, 0, stream>>>(x_hi, x_lo, W1hi, W1hi, h1bf, NN, D1, IN_F);
    al_kernel<H1, HID1><<<NN, H1 * 64, 0, stream>>>(h1bf, a_s1, a_d1, als1, ald1);
    agg1_kernel<<<NN, 256, 0, stream>>>(h1bf, als1, ald1, row_ptr, colidx, b1, h1hi, h1lo);

    gemm_mfma<3><<<dim3(D2 / BN, NN / BM), 256, 0, stream>>>(h1hi, h1lo, W2hi, W2lo, h2bf, NN, D2, D1);
    al_kernel<H2, OUT2><<<NN, H2 * 64, 0, stream>>>(h2bf, a_s2, a_d2, als2, ald2);
    agg2_kernel<<<NN, 256, 0, stream>>>(h2bf, als2, ald2, row_ptr, colidx, b2, batch, h2out, pooled);

    final_kernel<<<NB, 256, 0, stream>>>(pooled, n_g, e_cnt, projW, projb, lng, lnb,
                                         rhW1, rhb1, rhW2, rhb2, out_se, out_risk);
}

// Round 8
// 532.898 us; speedup vs baseline: 1.8023x; 1.0866x over previous
//
#include <hip/hip_runtime.h>
#include <math.h>

#define NN    16384
#define EE    262144
#define ET    (EE + NN)      // edges + self loops
#define NB    8
#define IN_F  768
#define HID1  256
#define H1    4
#define D1    (H1*HID1)      // 1024
#define OUT2  128
#define H2    2
#define D2    (H2*OUT2)      // 256

typedef __attribute__((ext_vector_type(8))) short short8;
typedef __attribute__((ext_vector_type(4))) float f32x4;

__device__ __forceinline__ unsigned short f2bf(float v) {
    unsigned u = __float_as_uint(v);
    u = (u + 0x7FFFu + ((u >> 16) & 1u)) >> 16;
    return (unsigned short)u;
}
__device__ __forceinline__ float bf2f(unsigned short b) {
    return __uint_as_float((unsigned)b << 16);
}

// ---------------- CSR build ----------------

__global__ void hist_kernel(const int* __restrict__ ei, const int* __restrict__ batch,
                            int* __restrict__ deg, int* __restrict__ n_g, int* __restrict__ e_cnt) {
    __shared__ int le[NB], ln[NB];
    int tid = threadIdx.x;
    if (tid < NB) { le[tid] = 0; ln[tid] = 0; }
    __syncthreads();
    int t = blockIdx.x * blockDim.x + tid;
    if (t < EE) {
        int s = ei[t];
        int d = ei[EE + t];
        atomicAdd(&deg[d], 1);
        atomicAdd(&le[batch[s]], 1);
    }
    if (t < NN) {
        atomicAdd(&ln[batch[t]], 1);
    }
    __syncthreads();
    if (tid < NB) {
        if (le[tid]) atomicAdd(&e_cnt[tid], le[tid]);
        if (ln[tid]) atomicAdd(&n_g[tid], ln[tid]);
    }
}

__global__ __launch_bounds__(1024) void scan_kernel(const int* __restrict__ deg, int* __restrict__ row_ptr) {
    __shared__ int sums[1024];
    int t = threadIdx.x;
    int base = t * 16;
    int local[16];
    int acc = 0;
#pragma unroll
    for (int i = 0; i < 16; i++) { local[i] = acc; acc += deg[base + i] + 1; }  // +1 = self loop
    sums[t] = acc;
    __syncthreads();
    for (int off = 1; off < 1024; off <<= 1) {
        int v = (t >= off) ? sums[t - off] : 0;
        __syncthreads();
        sums[t] += v;
        __syncthreads();
    }
    int prev = (t == 0) ? 0 : sums[t - 1];
#pragma unroll
    for (int i = 0; i < 16; i++) row_ptr[base + i] = prev + local[i];
    if (t == 1023) row_ptr[NN] = sums[1023];
}

__global__ void scatter_kernel(const int* __restrict__ ei, const int* __restrict__ row_ptr,
                               int* __restrict__ cursor, int* __restrict__ colidx) {
    int t = blockIdx.x * blockDim.x + threadIdx.x;
    if (t >= ET) return;
    int s, d;
    if (t < EE) { s = ei[t]; d = ei[EE + t]; }
    else        { s = d = t - EE; }
    int pos = row_ptr[d] + atomicAdd(&cursor[d], 1);
    colidx[pos] = s;
}

// ---------------- fp32 -> bf16 splits ----------------

__global__ void split_kernel(const float* __restrict__ in, unsigned short* __restrict__ hi,
                             unsigned short* __restrict__ lo, int n4) {
    int i = blockIdx.x * blockDim.x + threadIdx.x;
    if (i >= n4) return;
    float4 v = ((const float4*)in)[i];
    ushort4 h, l;
    h.x = f2bf(v.x); l.x = f2bf(v.x - bf2f(h.x));
    h.y = f2bf(v.y); l.y = f2bf(v.y - bf2f(h.y));
    h.z = f2bf(v.z); l.z = f2bf(v.z - bf2f(h.z));
    h.w = f2bf(v.w); l.w = f2bf(v.w - bf2f(h.w));
    ((ushort4*)hi)[i] = h;
    ((ushort4*)lo)[i] = l;
}

__global__ void tobf_kernel(const float* __restrict__ in, unsigned short* __restrict__ hi, int n4) {
    int i = blockIdx.x * blockDim.x + threadIdx.x;
    if (i >= n4) return;
    float4 v = ((const float4*)in)[i];
    ushort4 h;
    h.x = f2bf(v.x); h.y = f2bf(v.y); h.z = f2bf(v.z); h.w = f2bf(v.w);
    ((ushort4*)hi)[i] = h;
}

// ---------------- bf16 split MFMA GEMM, bf16 output ----------------

__device__ __forceinline__ void ld_lds16(const unsigned short* g, unsigned short* l) {
    __builtin_amdgcn_global_load_lds((__attribute__((address_space(1))) void*)g,
                                     (__attribute__((address_space(3))) void*)l, 16, 0, 0);
}

#define BM 128
#define BN 128
#define BK 32

template <int TERMS>
__global__ __launch_bounds__(256) void gemm_mfma(const unsigned short* __restrict__ Ahi,
                                                 const unsigned short* __restrict__ Alo,
                                                 const unsigned short* __restrict__ Bhi,
                                                 const unsigned short* __restrict__ Blo,
                                                 unsigned short* __restrict__ Cb,
                                                 int M, int N, int K) {
    __shared__ __align__(16) unsigned short sA[2][BM * BK];
    __shared__ __align__(16) unsigned short sB[2][BN * BK];
    int t = threadIdx.x;
    int lane = t & 63, wave = t >> 6;
    int bm = blockIdx.y * BM, bn = blockIdx.x * BN;
    int wm = (wave & 1) * 64, wn = (wave >> 1) * 64;

    const unsigned short* gbase;
    unsigned short* lbase;
    if      (wave == 0) { gbase = Ahi + (size_t)bm * K; lbase = sA[0]; }
    else if (wave == 1) { gbase = Alo + (size_t)bm * K; lbase = sA[1]; }
    else if (wave == 2) { gbase = Bhi + (size_t)bn * K; lbase = sB[0]; }
    else                { gbase = (TERMS == 3 ? Blo : Bhi) + (size_t)bn * K; lbase = sB[1]; }
    bool do_stage = (wave < 3) || (TERMS == 3);
    const unsigned short* gsrc = gbase + (size_t)(lane >> 2) * K + (lane & 3) * 8;

    f32x4 zero = {0.f, 0.f, 0.f, 0.f};
    f32x4 acc[4][4];
#pragma unroll
    for (int i = 0; i < 4; i++)
#pragma unroll
        for (int j = 0; j < 4; j++) acc[i][j] = zero;

    int row16 = lane & 15;
    int kq = (lane >> 4) * 8;

    for (int k0 = 0; k0 < K; k0 += BK) {
        if (do_stage) {
#pragma unroll
            for (int i = 0; i < 8; i++)
                ld_lds16(gsrc + k0 + (size_t)(i * 16) * K, lbase + i * 16 * BK);
        }
        __syncthreads();

        short8 ah[4], alo[4], bh[4], blo[4];
#pragma unroll
        for (int mt = 0; mt < 4; mt++) {
            int r = (wm + mt * 16 + row16) * BK + kq;
            ah[mt]  = *(const short8*)&sA[0][r];
            alo[mt] = *(const short8*)&sA[1][r];
        }
#pragma unroll
        for (int nt = 0; nt < 4; nt++) {
            int r = (wn + nt * 16 + row16) * BK + kq;
            bh[nt]  = *(const short8*)&sB[0][r];
            if (TERMS == 3) blo[nt] = *(const short8*)&sB[1][r];
        }
#pragma unroll
        for (int mt = 0; mt < 4; mt++)
#pragma unroll
            for (int nt = 0; nt < 4; nt++) {
                acc[mt][nt] = __builtin_amdgcn_mfma_f32_16x16x32_bf16(ah[mt],  bh[nt],  acc[mt][nt], 0, 0, 0);
                acc[mt][nt] = __builtin_amdgcn_mfma_f32_16x16x32_bf16(alo[mt], bh[nt],  acc[mt][nt], 0, 0, 0);
                if (TERMS == 3)
                    acc[mt][nt] = __builtin_amdgcn_mfma_f32_16x16x32_bf16(ah[mt], blo[nt], acc[mt][nt], 0, 0, 0);
            }
        __syncthreads();
    }

    int crow0 = bm + wm + (lane >> 4) * 4;
    int ccol0 = bn + wn + row16;
#pragma unroll
    for (int mt = 0; mt < 4; mt++)
#pragma unroll
        for (int nt = 0; nt < 4; nt++)
#pragma unroll
            for (int reg = 0; reg < 4; reg++)
                Cb[(size_t)(crow0 + mt * 16 + reg) * N + ccol0 + nt * 16] = f2bf(acc[mt][nt][reg]);
}

// ---------------- attention logits ----------------

template <int H, int CH>
__global__ void al_kernel(const unsigned short* __restrict__ h, const float* __restrict__ a_s,
                          const float* __restrict__ a_d, float* __restrict__ als,
                          float* __restrict__ ald) {
    int node = blockIdx.x;
    int wave = threadIdx.x >> 6;
    int lane = threadIdx.x & 63;
    const unsigned short* row = h + (size_t)node * (H * CH) + wave * CH;
    float ss = 0.f, sd = 0.f;
#pragma unroll
    for (int c = lane; c < CH; c += 64) {
        float v = bf2f(row[c]);
        ss += v * a_s[wave * CH + c];
        sd += v * a_d[wave * CH + c];
    }
#pragma unroll
    for (int off = 32; off; off >>= 1) {
        ss += __shfl_down(ss, off);
        sd += __shfl_down(sd, off);
    }
    if (lane == 0) {
        als[node * H + wave] = ss;
        ald[node * H + wave] = sd;
    }
}

__device__ __forceinline__ float leaky(float v) { return v > 0.f ? v : 0.2f * v; }
__device__ __forceinline__ float elu1(float v) { return v > 0.f ? v : (__expf(v) - 1.f); }

// ---------------- GAT layer 1 aggregation ----------------

__global__ __launch_bounds__(256) void agg1_kernel(const unsigned short* __restrict__ h,
                                                   const float* __restrict__ als,
                                                   const float* __restrict__ ald,
                                                   const int* __restrict__ row_ptr,
                                                   const int* __restrict__ colidx,
                                                   const float* __restrict__ bias,
                                                   unsigned short* __restrict__ out_hi,
                                                   unsigned short* __restrict__ out_lo) {
    int d = blockIdx.x;
    int t = threadIdx.x;
    int lane = t & 63, wave = t >> 6;
    int start = row_ptr[d], end = row_ptr[d + 1];

    __shared__ float ald_l[H1];
    __shared__ float wred[4][H1];
    __shared__ float sm[H1], sinv[H1];
    __shared__ int   s_src[64];
    __shared__ float s_w[64 * H1];

    if (t < H1) ald_l[t] = ald[d * H1 + t];
    __syncthreads();

    float mx[H1] = {-1e30f, -1e30f, -1e30f, -1e30f};
    for (int e = start + t; e < end; e += 256) {
        int s = colidx[e];
        const float* as = als + s * H1;
#pragma unroll
        for (int hh = 0; hh < H1; hh++)
            mx[hh] = fmaxf(mx[hh], leaky(as[hh] + ald_l[hh]));
    }
#pragma unroll
    for (int hh = 0; hh < H1; hh++)
#pragma unroll
        for (int off = 32; off; off >>= 1)
            mx[hh] = fmaxf(mx[hh], __shfl_down(mx[hh], off));
    if (lane == 0) {
#pragma unroll
        for (int hh = 0; hh < H1; hh++) wred[wave][hh] = mx[hh];
    }
    __syncthreads();
    if (t < H1) sm[t] = fmaxf(fmaxf(wred[0][t], wred[1][t]), fmaxf(wred[2][t], wred[3][t]));
    __syncthreads();

    float dn[H1] = {0.f, 0.f, 0.f, 0.f};
    for (int e = start + t; e < end; e += 256) {
        int s = colidx[e];
        const float* as = als + s * H1;
#pragma unroll
        for (int hh = 0; hh < H1; hh++)
            dn[hh] += __expf(leaky(as[hh] + ald_l[hh]) - sm[hh]);
    }
#pragma unroll
    for (int hh = 0; hh < H1; hh++)
#pragma unroll
        for (int off = 32; off; off >>= 1)
            dn[hh] += __shfl_down(dn[hh], off);
    if (lane == 0) {
#pragma unroll
        for (int hh = 0; hh < H1; hh++) wred[wave][hh] = dn[hh];
    }
    __syncthreads();
    if (t < H1) sinv[t] = 1.f / (wred[0][t] + wred[1][t] + wred[2][t] + wred[3][t] + 1e-16f);
    __syncthreads();

    // pass 3: weighted accumulate, chunked; k-loop unrolled x2
    float4 acc0 = make_float4(0.f, 0.f, 0.f, 0.f);
    float4 acc1 = make_float4(0.f, 0.f, 0.f, 0.f);
    int myh = t >> 6;
    for (int base = start; base < end; base += 64) {
        int ne = min(64, end - base);
        if (t < ne * H1) {
            int ei = t >> 2, hh = t & 3;
            int s = colidx[base + ei];
            if (hh == 0) s_src[ei] = s;
            float v = leaky(als[s * H1 + hh] + ald_l[hh]);
            s_w[(ei << 2) + hh] = __expf(v - sm[hh]) * sinv[hh];
        }
        __syncthreads();
        int k = 0;
        for (; k + 1 < ne; k += 2) {
            int s0 = s_src[k], s1 = s_src[k + 1];
            float w0 = s_w[(k << 2) + myh], w1 = s_w[((k + 1) << 2) + myh];
            ushort4 h0 = *(const ushort4*)(h + (size_t)s0 * D1 + t * 4);
            ushort4 h1 = *(const ushort4*)(h + (size_t)s1 * D1 + t * 4);
            acc0.x += w0 * bf2f(h0.x); acc0.y += w0 * bf2f(h0.y);
            acc0.z += w0 * bf2f(h0.z); acc0.w += w0 * bf2f(h0.w);
            acc1.x += w1 * bf2f(h1.x); acc1.y += w1 * bf2f(h1.y);
            acc1.z += w1 * bf2f(h1.z); acc1.w += w1 * bf2f(h1.w);
        }
        if (k < ne) {
            int s0 = s_src[k];
            float w0 = s_w[(k << 2) + myh];
            ushort4 h0 = *(const ushort4*)(h + (size_t)s0 * D1 + t * 4);
            acc0.x += w0 * bf2f(h0.x); acc0.y += w0 * bf2f(h0.y);
            acc0.z += w0 * bf2f(h0.z); acc0.w += w0 * bf2f(h0.w);
        }
        __syncthreads();
    }
    float4 acc;
    acc.x = acc0.x + acc1.x; acc.y = acc0.y + acc1.y;
    acc.z = acc0.z + acc1.z; acc.w = acc0.w + acc1.w;

    float4 bv = *(const float4*)(bias + t * 4);
    float4 o;
    o.x = elu1(acc.x + bv.x); o.y = elu1(acc.y + bv.y);
    o.z = elu1(acc.z + bv.z); o.w = elu1(acc.w + bv.w);
    ushort4 oh, ol;
    oh.x = f2bf(o.x); ol.x = f2bf(o.x - bf2f(oh.x));
    oh.y = f2bf(o.y); ol.y = f2bf(o.y - bf2f(oh.y));
    oh.z = f2bf(o.z); ol.z = f2bf(o.z - bf2f(oh.z));
    oh.w = f2bf(o.w); ol.w = f2bf(o.w - bf2f(oh.w));
    *(ushort4*)(out_hi + (size_t)d * D1 + t * 4) = oh;
    *(ushort4*)(out_lo + (size_t)d * D1 + t * 4) = ol;
}

// ---------------- GAT layer 2 aggregation (R4 structure, NO pooled atomics) ----------------

__global__ __launch_bounds__(256) void agg2_kernel(const unsigned short* __restrict__ h,
                                                   const float* __restrict__ als,
                                                   const float* __restrict__ ald,
                                                   const int* __restrict__ row_ptr,
                                                   const int* __restrict__ colidx,
                                                   const float* __restrict__ bias,
                                                   float* __restrict__ out) {
    int d = blockIdx.x;
    int t = threadIdx.x;
    int lane = t & 63, wave = t >> 6;
    int start = row_ptr[d], end = row_ptr[d + 1];

    __shared__ float ald_l[H2];
    __shared__ float wred[4][H2];
    __shared__ float sm[H2], sinv[H2];
    __shared__ int   s_src[128];
    __shared__ float s_w[128 * H2];
    __shared__ float red[256];

    if (t < H2) ald_l[t] = ald[d * H2 + t];
    __syncthreads();

    float mx[H2] = {-1e30f, -1e30f};
    for (int e = start + t; e < end; e += 256) {
        int s = colidx[e];
        const float* as = als + s * H2;
#pragma unroll
        for (int hh = 0; hh < H2; hh++)
            mx[hh] = fmaxf(mx[hh], leaky(as[hh] + ald_l[hh]));
    }
#pragma unroll
    for (int hh = 0; hh < H2; hh++)
#pragma unroll
        for (int off = 32; off; off >>= 1)
            mx[hh] = fmaxf(mx[hh], __shfl_down(mx[hh], off));
    if (lane == 0) {
#pragma unroll
        for (int hh = 0; hh < H2; hh++) wred[wave][hh] = mx[hh];
    }
    __syncthreads();
    if (t < H2) sm[t] = fmaxf(fmaxf(wred[0][t], wred[1][t]), fmaxf(wred[2][t], wred[3][t]));
    __syncthreads();

    float dn[H2] = {0.f, 0.f};
    for (int e = start + t; e < end; e += 256) {
        int s = colidx[e];
        const float* as = als + s * H2;
#pragma unroll
        for (int hh = 0; hh < H2; hh++)
            dn[hh] += __expf(leaky(as[hh] + ald_l[hh]) - sm[hh]);
    }
#pragma unroll
    for (int hh = 0; hh < H2; hh++)
#pragma unroll
        for (int off = 32; off; off >>= 1)
            dn[hh] += __shfl_down(dn[hh], off);
    if (lane == 0) {
#pragma unroll
        for (int hh = 0; hh < H2; hh++) wred[wave][hh] = dn[hh];
    }
    __syncthreads();
    if (t < H2) sinv[t] = 1.f / (wred[0][t] + wred[1][t] + wred[2][t] + wred[3][t] + 1e-16f);
    __syncthreads();

    // pass 3: k-loop unrolled x4 with independent accumulators
    float a0 = 0.f, a1 = 0.f, a2 = 0.f, a3 = 0.f;
    int myh = t >> 7;
    for (int base = start; base < end; base += 128) {
        int ne = min(128, end - base);
        if (t < ne * 2) {
            int ei = t >> 1, hh = t & 1;
            int s = colidx[base + ei];
            if (hh == 0) s_src[ei] = s;
            float v = leaky(als[s * H2 + hh] + ald_l[hh]);
            s_w[(ei << 1) + hh] = __expf(v - sm[hh]) * sinv[hh];
        }
        __syncthreads();
        int k = 0;
        for (; k + 3 < ne; k += 4) {
            int s0 = s_src[k],     s1 = s_src[k + 1];
            int s2 = s_src[k + 2], s3 = s_src[k + 3];
            float w0 = s_w[(k << 1) + myh],       w1 = s_w[((k + 1) << 1) + myh];
            float w2 = s_w[((k + 2) << 1) + myh], w3 = s_w[((k + 3) << 1) + myh];
            unsigned short v0 = h[(size_t)s0 * D2 + t];
            unsigned short v1 = h[(size_t)s1 * D2 + t];
            unsigned short v2 = h[(size_t)s2 * D2 + t];
            unsigned short v3 = h[(size_t)s3 * D2 + t];
            a0 += w0 * bf2f(v0); a1 += w1 * bf2f(v1);
            a2 += w2 * bf2f(v2); a3 += w3 * bf2f(v3);
        }
        for (; k < ne; k++) {
            a0 += s_w[(k << 1) + myh] * bf2f(h[(size_t)s_src[k] * D2 + t]);
        }
        __syncthreads();
    }
    red[t] = (a0 + a1) + (a2 + a3);
    __syncthreads();
    if (t < 128) {
        float v = (red[t] + red[t + 128]) * 0.5f + bias[t];
        out[(size_t)d * OUT2 + t] = elu1(v);
    }
}

// ---------------- pooling: per-graph sum of h2out (batch is SORTED) ----------------
// 64 blocks x 256 nodes each; thread t owns channel t&127, node parity t>>7.
// Block-local accumulation with graph-change flush -> ~17K atomics total
// (vs 2.1M when fused into agg2 = ~115us of line-serialized atomic drain).

__global__ __launch_bounds__(256) void pool_kernel(const float* __restrict__ h2,
                                                   const int* __restrict__ batch,
                                                   float* __restrict__ pooled) {
    int c = threadIdx.x & 127;
    int half = threadIdx.x >> 7;
    int n0 = blockIdx.x * 256 + half;
    int nend = blockIdx.x * 256 + 256;
    float acc = 0.f;
    int curg = batch[n0];
    for (int n = n0; n < nend; n += 2) {
        int g = batch[n];
        if (g != curg) {
            atomicAdd(&pooled[curg * OUT2 + c], acc);
            acc = 0.f; curg = g;
        }
        acc += h2[(size_t)n * OUT2 + c];
    }
    atomicAdd(&pooled[curg * OUT2 + c], acc);
}

// ---------------- per-graph head: proj + LN + risk MLP ----------------

__global__ __launch_bounds__(256) void final_kernel(const float* __restrict__ pooled_sum,
                                                    const int* __restrict__ n_g_i,
                                                    const int* __restrict__ e_cnt,
                                                    const float* __restrict__ projW,
                                                    const float* __restrict__ projb,
                                                    const float* __restrict__ lng,
                                                    const float* __restrict__ lnb,
                                                    const float* __restrict__ rhW1,
                                                    const float* __restrict__ rhb1,
                                                    const float* __restrict__ rhW2,
                                                    const float* __restrict__ rhb2,
                                                    float* __restrict__ out_se,
                                                    float* __restrict__ out_risk) {
    int b = blockIdx.x;
    int t = threadIdx.x;
    __shared__ float pooled[OUT2];
    __shared__ float pe[768];
    __shared__ float red[256];
    __shared__ float hid[32];
    __shared__ float stat_mu, stat_inv;

    float ng = (float)n_g_i[b];
    if (t < OUT2) pooled[t] = pooled_sum[b * OUT2 + t] / fmaxf(ng, 1.0f);
    __syncthreads();

    for (int j = t; j < 768; j += 256) {
        const float* wr = projW + (size_t)j * OUT2;
        float s = projb[j];
        for (int c = 0; c < OUT2; c++) s += pooled[c] * wr[c];
        pe[j] = s;
    }
    __syncthreads();

    float ls = 0.f, lq = 0.f;
    for (int j = t; j < 768; j += 256) { float v = pe[j]; ls += v; lq += v * v; }
    red[t] = ls;
    __syncthreads();
    for (int off = 128; off; off >>= 1) { if (t < off) red[t] += red[t + off]; __syncthreads(); }
    float tot = red[0];
    __syncthreads();
    red[t] = lq;
    __syncthreads();
    for (int off = 128; off; off >>= 1) { if (t < off) red[t] += red[t + off]; __syncthreads(); }
    float totq = red[0];
    if (t == 0) {
        float mu = tot / 768.f;
        float var = totq / 768.f - mu * mu;
        stat_mu = mu;
        stat_inv = 1.f / sqrtf(var + 1e-5f);
    }
    __syncthreads();
    float mu = stat_mu, inv = stat_inv;
    for (int j = t; j < 768; j += 256)
        out_se[(size_t)b * 768 + j] = (pe[j] - mu) * inv * lng[j] + lnb[j];

    float s0 = (float)e_cnt[b] / (ng + 1e-6f);
    float s1 = logf(ng + 1.0f);
    if (t < 32) {
        const float* wr = rhW1 + t * (OUT2 + 2);
        float s = rhb1[t];
        for (int c = 0; c < OUT2; c++) s += pooled[c] * wr[c];
        s += s0 * wr[OUT2] + s1 * wr[OUT2 + 1];
        hid[t] = fmaxf(s, 0.f);
    }
    __syncthreads();
    if (t == 0) {
        float s = rhb2[0];
        for (int k = 0; k < 32; k++) s += hid[k] * rhW2[k];
        out_risk[b] = 1.f / (1.f + __expf(-s));
    }
}

// ---------------- launch ----------------

extern "C" void kernel_launch(void* const* d_in, const int* in_sizes, int n_in,
                              void* d_out, int out_size, void* d_ws, size_t ws_size,
                              hipStream_t stream) {
    const float* x     = (const float*)d_in[0];
    const int*   ei    = (const int*)  d_in[1];
    const int*   batch = (const int*)  d_in[2];
    const float* W1    = (const float*)d_in[3];
    const float* a_s1  = (const float*)d_in[4];
    const float* a_d1  = (const float*)d_in[5];
    const float* b1    = (const float*)d_in[6];
    const float* W2    = (const float*)d_in[7];
    const float* a_s2  = (const float*)d_in[8];
    const float* a_d2  = (const float*)d_in[9];
    const float* b2    = (const float*)d_in[10];
    const float* projW = (const float*)d_in[11];
    const float* projb = (const float*)d_in[12];
    const float* lng   = (const float*)d_in[13];
    const float* lnb   = (const float*)d_in[14];
    const float* rhW1  = (const float*)d_in[15];
    const float* rhb1  = (const float*)d_in[16];
    const float* rhW2  = (const float*)d_in[17];
    const float* rhb2  = (const float*)d_in[18];

    char* ws = (char*)d_ws;
    size_t off = 0;
    auto alloc = [&](size_t bytes) -> void* {
        void* p = ws + off;
        off += (bytes + 255) & ~(size_t)255;
        return p;
    };

    unsigned short* regionA = (unsigned short*)alloc((size_t)2 * NN * D1 * 2);
    unsigned short* x_hi = regionA;
    unsigned short* x_lo = regionA + (size_t)NN * IN_F;
    unsigned short* h1hi = regionA;
    unsigned short* h1lo = regionA + (size_t)NN * D1;

    unsigned short* h1bf = (unsigned short*)alloc((size_t)NN * D1 * 2);
    unsigned short* h2bf = (unsigned short*)alloc((size_t)NN * D2 * 2);
    unsigned short* W1hi = (unsigned short*)alloc((size_t)D1 * IN_F * 2);
    unsigned short* W2hi = (unsigned short*)alloc((size_t)D2 * D1 * 2);
    unsigned short* W2lo = (unsigned short*)alloc((size_t)D2 * D1 * 2);
    float* als1   = (float*)alloc((size_t)NN * H1 * 4);
    float* ald1   = (float*)alloc((size_t)NN * H1 * 4);
    float* als2   = (float*)alloc((size_t)NN * H2 * 4);
    float* ald2   = (float*)alloc((size_t)NN * H2 * 4);
    int*   row_ptr= (int*)  alloc((size_t)(NN + 1) * 4);
    int*   colidx = (int*)  alloc((size_t)ET * 4);
    size_t zoff = off;
    int*   deg    = (int*)  alloc((size_t)NN * 4);
    int*   cursor = (int*)  alloc((size_t)NN * 4);
    int*   n_g    = (int*)  alloc((size_t)NB * 4);
    int*   e_cnt  = (int*)  alloc((size_t)NB * 4);
    float* pooled = (float*)alloc((size_t)NB * OUT2 * 4);
    size_t zbytes = off - zoff;

    float* out_se   = (float*)d_out;
    float* h2out    = out_se + NB * 768;
    float* out_risk = h2out + (size_t)NN * OUT2;

    hipMemsetAsync(ws + zoff, 0, zbytes, stream);

    hist_kernel<<<(EE + 255) / 256, 256, 0, stream>>>(ei, batch, deg, n_g, e_cnt);
    scan_kernel<<<1, 1024, 0, stream>>>(deg, row_ptr);
    scatter_kernel<<<(ET + 255) / 256, 256, 0, stream>>>(ei, row_ptr, cursor, colidx);

    split_kernel<<<((NN * IN_F / 4) + 255) / 256, 256, 0, stream>>>(x, x_hi, x_lo, NN * IN_F / 4);
    tobf_kernel<<<((D1 * IN_F / 4) + 255) / 256, 256, 0, stream>>>(W1, W1hi, D1 * IN_F / 4);
    split_kernel<<<((D2 * D1 / 4) + 255) / 256, 256, 0, stream>>>(W2, W2hi, W2lo, D2 * D1 / 4);

    gemm_mfma<2><<<dim3(D1 / BN, NN / BM), 256, 0, stream>>>(x_hi, x_lo, W1hi, W1hi, h1bf, NN, D1, IN_F);
    al_kernel<H1, HID1><<<NN, H1 * 64, 0, stream>>>(h1bf, a_s1, a_d1, als1, ald1);
    agg1_kernel<<<NN, 256, 0, stream>>>(h1bf, als1, ald1, row_ptr, colidx, b1, h1hi, h1lo);

    gemm_mfma<3><<<dim3(D2 / BN, NN / BM), 256, 0, stream>>>(h1hi, h1lo, W2hi, W2lo, h2bf, NN, D2, D1);
    al_kernel<H2, OUT2><<<NN, H2 * 64, 0, stream>>>(h2bf, a_s2, a_d2, als2, ald2);
    agg2_kernel<<<NN, 256, 0, stream>>>(h2bf, als2, ald2, row_ptr, colidx, b2, h2out);

    pool_kernel<<<NN / 256, 256, 0, stream>>>(h2out, batch, pooled);

    final_kernel<<<NB, 256, 0, stream>>>(pooled, n_g, e_cnt, projW, projb, lng, lnb,
                                         rhW1, rhb1, rhW2, rhb2, out_se, out_risk);
}

// Round 9
// 505.068 us; speedup vs baseline: 1.9016x; 1.0551x over previous
//
#include <hip/hip_runtime.h>
#include <math.h>

#define NN    16384
#define EE    262144
#define ET    (EE + NN)      // edges + self loops
#define NB    8
#define IN_F  768
#define HID1  256
#define H1    4
#define D1    (H1*HID1)      // 1024
#define OUT2  128
#define H2    2
#define D2    (H2*OUT2)      // 256

typedef __attribute__((ext_vector_type(8))) short short8;
typedef __attribute__((ext_vector_type(4))) float f32x4;

__device__ __forceinline__ unsigned short f2bf(float v) {
    unsigned u = __float_as_uint(v);
    u = (u + 0x7FFFu + ((u >> 16) & 1u)) >> 16;
    return (unsigned short)u;
}
__device__ __forceinline__ float bf2f(unsigned short b) {
    return __uint_as_float((unsigned)b << 16);
}

// ---------------- CSR build ----------------

__global__ void hist_kernel(const int* __restrict__ ei, const int* __restrict__ batch,
                            int* __restrict__ deg, int* __restrict__ n_g, int* __restrict__ e_cnt) {
    __shared__ int le[NB], ln[NB];
    int tid = threadIdx.x;
    if (tid < NB) { le[tid] = 0; ln[tid] = 0; }
    __syncthreads();
    int t = blockIdx.x * blockDim.x + tid;
    if (t < EE) {
        int s = ei[t];
        int d = ei[EE + t];
        atomicAdd(&deg[d], 1);
        atomicAdd(&le[batch[s]], 1);
    }
    if (t < NN) {
        atomicAdd(&ln[batch[t]], 1);
    }
    __syncthreads();
    if (tid < NB) {
        if (le[tid]) atomicAdd(&e_cnt[tid], le[tid]);
        if (ln[tid]) atomicAdd(&n_g[tid], ln[tid]);
    }
}

__global__ __launch_bounds__(1024) void scan_kernel(const int* __restrict__ deg, int* __restrict__ row_ptr) {
    __shared__ int sums[1024];
    int t = threadIdx.x;
    int base = t * 16;
    int local[16];
    int acc = 0;
#pragma unroll
    for (int i = 0; i < 16; i++) { local[i] = acc; acc += deg[base + i] + 1; }  // +1 = self loop
    sums[t] = acc;
    __syncthreads();
    for (int off = 1; off < 1024; off <<= 1) {
        int v = (t >= off) ? sums[t - off] : 0;
        __syncthreads();
        sums[t] += v;
        __syncthreads();
    }
    int prev = (t == 0) ? 0 : sums[t - 1];
#pragma unroll
    for (int i = 0; i < 16; i++) row_ptr[base + i] = prev + local[i];
    if (t == 1023) row_ptr[NN] = sums[1023];
}

__global__ void scatter_kernel(const int* __restrict__ ei, const int* __restrict__ row_ptr,
                               int* __restrict__ cursor, int* __restrict__ colidx) {
    int t = blockIdx.x * blockDim.x + threadIdx.x;
    if (t >= ET) return;
    int s, d;
    if (t < EE) { s = ei[t]; d = ei[EE + t]; }
    else        { s = d = t - EE; }
    int pos = row_ptr[d] + atomicAdd(&cursor[d], 1);
    colidx[pos] = s;
}

// ---------------- fp32 -> bf16 splits ----------------

__global__ void split_kernel(const float* __restrict__ in, unsigned short* __restrict__ hi,
                             unsigned short* __restrict__ lo, int n4) {
    int i = blockIdx.x * blockDim.x + threadIdx.x;
    if (i >= n4) return;
    float4 v = ((const float4*)in)[i];
    ushort4 h, l;
    h.x = f2bf(v.x); l.x = f2bf(v.x - bf2f(h.x));
    h.y = f2bf(v.y); l.y = f2bf(v.y - bf2f(h.y));
    h.z = f2bf(v.z); l.z = f2bf(v.z - bf2f(h.z));
    h.w = f2bf(v.w); l.w = f2bf(v.w - bf2f(h.w));
    ((ushort4*)hi)[i] = h;
    ((ushort4*)lo)[i] = l;
}

__global__ void tobf_kernel(const float* __restrict__ in, unsigned short* __restrict__ hi, int n4) {
    int i = blockIdx.x * blockDim.x + threadIdx.x;
    if (i >= n4) return;
    float4 v = ((const float4*)in)[i];
    ushort4 h;
    h.x = f2bf(v.x); h.y = f2bf(v.y); h.z = f2bf(v.z); h.w = f2bf(v.w);
    ((ushort4*)hi)[i] = h;
}

// ---------------- bf16 split MFMA GEMM, bf16 output ----------------
// XOR-swizzled LDS: LDS[row][pc] holds global K-chunk (pc ^ ((row>>1)&3)); the
// swizzle is applied on the global-source side of global_load_lds (dest must be
// wave-uniform base + lane*16B) and undone in the ds_read addressing. Kills the
// 8-way bank conflict of the BK=32 row stride (was 4.7M conflict cycles).
// XCD-aware block swizzle: b%8 selects the row-stripe's XCD so all col-blocks
// of one A-stripe are consecutive on ONE XCD -> A-stripe stays L2-resident
// (FETCH was 222MB vs 50MB logical).

__device__ __forceinline__ void ld_lds16(const unsigned short* g, unsigned short* l) {
    __builtin_amdgcn_global_load_lds((__attribute__((address_space(1))) void*)g,
                                     (__attribute__((address_space(3))) void*)l, 16, 0, 0);
}

#define BM 128
#define BN 128
#define BK 32

template <int TERMS>
__global__ __launch_bounds__(256) void gemm_mfma(const unsigned short* __restrict__ Ahi,
                                                 const unsigned short* __restrict__ Alo,
                                                 const unsigned short* __restrict__ Bhi,
                                                 const unsigned short* __restrict__ Blo,
                                                 unsigned short* __restrict__ Cb,
                                                 int M, int N, int K) {
    __shared__ __align__(16) unsigned short sA[2][BM * BK];
    __shared__ __align__(16) unsigned short sB[2][BN * BK];
    int t = threadIdx.x;
    int lane = t & 63, wave = t >> 6;

    // XCD swizzle: row-stripe r = (b/8/NC)*8 + b%8, col c = (b/8)%NC
    int NC = N / BN;
    int b = blockIdx.x;
    int xcd = b & 7;
    int idx = b >> 3;
    int c = idx % NC;
    int rg = idx / NC;
    int bm = (rg * 8 + xcd) * BM;
    int bn = c * BN;

    int wm = (wave & 1) * 64, wn = (wave >> 1) * 64;

    const unsigned short* gbase;
    unsigned short* lbase;
    if      (wave == 0) { gbase = Ahi + (size_t)bm * K; lbase = sA[0]; }
    else if (wave == 1) { gbase = Alo + (size_t)bm * K; lbase = sA[1]; }
    else if (wave == 2) { gbase = Bhi + (size_t)bn * K; lbase = sB[0]; }
    else                { gbase = (TERMS == 3 ? Blo : Bhi) + (size_t)bn * K; lbase = sB[1]; }
    bool do_stage = (wave < 3) || (TERMS == 3);
    // staging: lane -> row = lane>>2, phys chunk = lane&3 (LDS dest fixed);
    // fetch global chunk (lane&3) ^ ((row>>1)&3); row>>1 = lane>>3.
    int schunk = (lane & 3) ^ ((lane >> 3) & 3);
    const unsigned short* gsrc = gbase + (size_t)(lane >> 2) * K + schunk * 8;

    f32x4 zero = {0.f, 0.f, 0.f, 0.f};
    f32x4 acc[4][4];
#pragma unroll
    for (int i = 0; i < 4; i++)
#pragma unroll
        for (int j = 0; j < 4; j++) acc[i][j] = zero;

    int row16 = lane & 15;
    // reader: logical chunk kc = lane>>4 lives at phys chunk kc ^ ((row16>>1)&3)
    int kq = ((lane >> 4) ^ ((row16 >> 1) & 3)) * 8;

    for (int k0 = 0; k0 < K; k0 += BK) {
        if (do_stage) {
#pragma unroll
            for (int i = 0; i < 8; i++)
                ld_lds16(gsrc + k0 + (size_t)(i * 16) * K, lbase + i * 16 * BK);
        }
        __syncthreads();

        short8 ah[4], alo[4], bh[4], blo[4];
#pragma unroll
        for (int mt = 0; mt < 4; mt++) {
            int r = (wm + mt * 16 + row16) * BK + kq;
            ah[mt]  = *(const short8*)&sA[0][r];
            alo[mt] = *(const short8*)&sA[1][r];
        }
#pragma unroll
        for (int nt = 0; nt < 4; nt++) {
            int r = (wn + nt * 16 + row16) * BK + kq;
            bh[nt]  = *(const short8*)&sB[0][r];
            if (TERMS == 3) blo[nt] = *(const short8*)&sB[1][r];
        }
#pragma unroll
        for (int mt = 0; mt < 4; mt++)
#pragma unroll
            for (int nt = 0; nt < 4; nt++) {
                acc[mt][nt] = __builtin_amdgcn_mfma_f32_16x16x32_bf16(ah[mt],  bh[nt],  acc[mt][nt], 0, 0, 0);
                acc[mt][nt] = __builtin_amdgcn_mfma_f32_16x16x32_bf16(alo[mt], bh[nt],  acc[mt][nt], 0, 0, 0);
                if (TERMS == 3)
                    acc[mt][nt] = __builtin_amdgcn_mfma_f32_16x16x32_bf16(ah[mt], blo[nt], acc[mt][nt], 0, 0, 0);
            }
        __syncthreads();
    }

    int crow0 = bm + wm + (lane >> 4) * 4;
    int ccol0 = bn + wn + row16;
#pragma unroll
    for (int mt = 0; mt < 4; mt++)
#pragma unroll
        for (int nt = 0; nt < 4; nt++)
#pragma unroll
            for (int reg = 0; reg < 4; reg++)
                Cb[(size_t)(crow0 + mt * 16 + reg) * N + ccol0 + nt * 16] = f2bf(acc[mt][nt][reg]);
}

// ---------------- attention logits ----------------

template <int H, int CH>
__global__ void al_kernel(const unsigned short* __restrict__ h, const float* __restrict__ a_s,
                          const float* __restrict__ a_d, float* __restrict__ als,
                          float* __restrict__ ald) {
    int node = blockIdx.x;
    int wave = threadIdx.x >> 6;
    int lane = threadIdx.x & 63;
    const unsigned short* row = h + (size_t)node * (H * CH) + wave * CH;
    float ss = 0.f, sd = 0.f;
#pragma unroll
    for (int c = lane; c < CH; c += 64) {
        float v = bf2f(row[c]);
        ss += v * a_s[wave * CH + c];
        sd += v * a_d[wave * CH + c];
    }
#pragma unroll
    for (int off = 32; off; off >>= 1) {
        ss += __shfl_down(ss, off);
        sd += __shfl_down(sd, off);
    }
    if (lane == 0) {
        als[node * H + wave] = ss;
        ald[node * H + wave] = sd;
    }
}

__device__ __forceinline__ float leaky(float v) { return v > 0.f ? v : 0.2f * v; }
__device__ __forceinline__ float elu1(float v) { return v > 0.f ? v : (__expf(v) - 1.f); }

// ---------------- GAT layer 1 aggregation (unroll-4 gather) ----------------

__global__ __launch_bounds__(256) void agg1_kernel(const unsigned short* __restrict__ h,
                                                   const float* __restrict__ als,
                                                   const float* __restrict__ ald,
                                                   const int* __restrict__ row_ptr,
                                                   const int* __restrict__ colidx,
                                                   const float* __restrict__ bias,
                                                   unsigned short* __restrict__ out_hi,
                                                   unsigned short* __restrict__ out_lo) {
    int d = blockIdx.x;
    int t = threadIdx.x;
    int lane = t & 63, wave = t >> 6;
    int start = row_ptr[d], end = row_ptr[d + 1];

    __shared__ float ald_l[H1];
    __shared__ float wred[4][H1];
    __shared__ float sm[H1], sinv[H1];
    __shared__ int   s_src[64];
    __shared__ float s_w[64 * H1];

    if (t < H1) ald_l[t] = ald[d * H1 + t];
    __syncthreads();

    float mx[H1] = {-1e30f, -1e30f, -1e30f, -1e30f};
    for (int e = start + t; e < end; e += 256) {
        int s = colidx[e];
        const float* as = als + s * H1;
#pragma unroll
        for (int hh = 0; hh < H1; hh++)
            mx[hh] = fmaxf(mx[hh], leaky(as[hh] + ald_l[hh]));
    }
#pragma unroll
    for (int hh = 0; hh < H1; hh++)
#pragma unroll
        for (int off = 32; off; off >>= 1)
            mx[hh] = fmaxf(mx[hh], __shfl_down(mx[hh], off));
    if (lane == 0) {
#pragma unroll
        for (int hh = 0; hh < H1; hh++) wred[wave][hh] = mx[hh];
    }
    __syncthreads();
    if (t < H1) sm[t] = fmaxf(fmaxf(wred[0][t], wred[1][t]), fmaxf(wred[2][t], wred[3][t]));
    __syncthreads();

    float dn[H1] = {0.f, 0.f, 0.f, 0.f};
    for (int e = start + t; e < end; e += 256) {
        int s = colidx[e];
        const float* as = als + s * H1;
#pragma unroll
        for (int hh = 0; hh < H1; hh++)
            dn[hh] += __expf(leaky(as[hh] + ald_l[hh]) - sm[hh]);
    }
#pragma unroll
    for (int hh = 0; hh < H1; hh++)
#pragma unroll
        for (int off = 32; off; off >>= 1)
            dn[hh] += __shfl_down(dn[hh], off);
    if (lane == 0) {
#pragma unroll
        for (int hh = 0; hh < H1; hh++) wred[wave][hh] = dn[hh];
    }
    __syncthreads();
    if (t < H1) sinv[t] = 1.f / (wred[0][t] + wred[1][t] + wred[2][t] + wred[3][t] + 1e-16f);
    __syncthreads();

    // pass 3: weighted accumulate, chunked; k-loop unrolled x4
    float4 acc0 = make_float4(0.f, 0.f, 0.f, 0.f);
    float4 acc1 = make_float4(0.f, 0.f, 0.f, 0.f);
    float4 acc2 = make_float4(0.f, 0.f, 0.f, 0.f);
    float4 acc3 = make_float4(0.f, 0.f, 0.f, 0.f);
    int myh = t >> 6;
    for (int base = start; base < end; base += 64) {
        int ne = min(64, end - base);
        if (t < ne * H1) {
            int ei = t >> 2, hh = t & 3;
            int s = colidx[base + ei];
            if (hh == 0) s_src[ei] = s;
            float v = leaky(als[s * H1 + hh] + ald_l[hh]);
            s_w[(ei << 2) + hh] = __expf(v - sm[hh]) * sinv[hh];
        }
        __syncthreads();
        int k = 0;
        for (; k + 3 < ne; k += 4) {
            int s0 = s_src[k],     s1 = s_src[k + 1];
            int s2 = s_src[k + 2], s3 = s_src[k + 3];
            float w0 = s_w[(k << 2) + myh],       w1 = s_w[((k + 1) << 2) + myh];
            float w2 = s_w[((k + 2) << 2) + myh], w3 = s_w[((k + 3) << 2) + myh];
            ushort4 h0 = *(const ushort4*)(h + (size_t)s0 * D1 + t * 4);
            ushort4 h1 = *(const ushort4*)(h + (size_t)s1 * D1 + t * 4);
            ushort4 h2 = *(const ushort4*)(h + (size_t)s2 * D1 + t * 4);
            ushort4 h3 = *(const ushort4*)(h + (size_t)s3 * D1 + t * 4);
            acc0.x += w0 * bf2f(h0.x); acc0.y += w0 * bf2f(h0.y);
            acc0.z += w0 * bf2f(h0.z); acc0.w += w0 * bf2f(h0.w);
            acc1.x += w1 * bf2f(h1.x); acc1.y += w1 * bf2f(h1.y);
            acc1.z += w1 * bf2f(h1.z); acc1.w += w1 * bf2f(h1.w);
            acc2.x += w2 * bf2f(h2.x); acc2.y += w2 * bf2f(h2.y);
            acc2.z += w2 * bf2f(h2.z); acc2.w += w2 * bf2f(h2.w);
            acc3.x += w3 * bf2f(h3.x); acc3.y += w3 * bf2f(h3.y);
            acc3.z += w3 * bf2f(h3.z); acc3.w += w3 * bf2f(h3.w);
        }
        for (; k < ne; k++) {
            int s0 = s_src[k];
            float w0 = s_w[(k << 2) + myh];
            ushort4 h0 = *(const ushort4*)(h + (size_t)s0 * D1 + t * 4);
            acc0.x += w0 * bf2f(h0.x); acc0.y += w0 * bf2f(h0.y);
            acc0.z += w0 * bf2f(h0.z); acc0.w += w0 * bf2f(h0.w);
        }
        __syncthreads();
    }
    float4 acc;
    acc.x = (acc0.x + acc1.x) + (acc2.x + acc3.x);
    acc.y = (acc0.y + acc1.y) + (acc2.y + acc3.y);
    acc.z = (acc0.z + acc1.z) + (acc2.z + acc3.z);
    acc.w = (acc0.w + acc1.w) + (acc2.w + acc3.w);

    float4 bv = *(const float4*)(bias + t * 4);
    float4 o;
    o.x = elu1(acc.x + bv.x); o.y = elu1(acc.y + bv.y);
    o.z = elu1(acc.z + bv.z); o.w = elu1(acc.w + bv.w);
    ushort4 oh, ol;
    oh.x = f2bf(o.x); ol.x = f2bf(o.x - bf2f(oh.x));
    oh.y = f2bf(o.y); ol.y = f2bf(o.y - bf2f(oh.y));
    oh.z = f2bf(o.z); ol.z = f2bf(o.z - bf2f(oh.z));
    oh.w = f2bf(o.w); ol.w = f2bf(o.w - bf2f(oh.w));
    *(ushort4*)(out_hi + (size_t)d * D1 + t * 4) = oh;
    *(ushort4*)(out_lo + (size_t)d * D1 + t * 4) = ol;
}

// ---------------- GAT layer 2 aggregation (no pooled atomics) ----------------

__global__ __launch_bounds__(256) void agg2_kernel(const unsigned short* __restrict__ h,
                                                   const float* __restrict__ als,
                                                   const float* __restrict__ ald,
                                                   const int* __restrict__ row_ptr,
                                                   const int* __restrict__ colidx,
                                                   const float* __restrict__ bias,
                                                   float* __restrict__ out) {
    int d = blockIdx.x;
    int t = threadIdx.x;
    int lane = t & 63, wave = t >> 6;
    int start = row_ptr[d], end = row_ptr[d + 1];

    __shared__ float ald_l[H2];
    __shared__ float wred[4][H2];
    __shared__ float sm[H2], sinv[H2];
    __shared__ int   s_src[128];
    __shared__ float s_w[128 * H2];
    __shared__ float red[256];

    if (t < H2) ald_l[t] = ald[d * H2 + t];
    __syncthreads();

    float mx[H2] = {-1e30f, -1e30f};
    for (int e = start + t; e < end; e += 256) {
        int s = colidx[e];
        const float* as = als + s * H2;
#pragma unroll
        for (int hh = 0; hh < H2; hh++)
            mx[hh] = fmaxf(mx[hh], leaky(as[hh] + ald_l[hh]));
    }
#pragma unroll
    for (int hh = 0; hh < H2; hh++)
#pragma unroll
        for (int off = 32; off; off >>= 1)
            mx[hh] = fmaxf(mx[hh], __shfl_down(mx[hh], off));
    if (lane == 0) {
#pragma unroll
        for (int hh = 0; hh < H2; hh++) wred[wave][hh] = mx[hh];
    }
    __syncthreads();
    if (t < H2) sm[t] = fmaxf(fmaxf(wred[0][t], wred[1][t]), fmaxf(wred[2][t], wred[3][t]));
    __syncthreads();

    float dn[H2] = {0.f, 0.f};
    for (int e = start + t; e < end; e += 256) {
        int s = colidx[e];
        const float* as = als + s * H2;
#pragma unroll
        for (int hh = 0; hh < H2; hh++)
            dn[hh] += __expf(leaky(as[hh] + ald_l[hh]) - sm[hh]);
    }
#pragma unroll
    for (int hh = 0; hh < H2; hh++)
#pragma unroll
        for (int off = 32; off; off >>= 1)
            dn[hh] += __shfl_down(dn[hh], off);
    if (lane == 0) {
#pragma unroll
        for (int hh = 0; hh < H2; hh++) wred[wave][hh] = dn[hh];
    }
    __syncthreads();
    if (t < H2) sinv[t] = 1.f / (wred[0][t] + wred[1][t] + wred[2][t] + wred[3][t] + 1e-16f);
    __syncthreads();

    // pass 3: k-loop unrolled x4 with independent accumulators
    float a0 = 0.f, a1 = 0.f, a2 = 0.f, a3 = 0.f;
    int myh = t >> 7;
    for (int base = start; base < end; base += 128) {
        int ne = min(128, end - base);
        if (t < ne * 2) {
            int ei = t >> 1, hh = t & 1;
            int s = colidx[base + ei];
            if (hh == 0) s_src[ei] = s;
            float v = leaky(als[s * H2 + hh] + ald_l[hh]);
            s_w[(ei << 1) + hh] = __expf(v - sm[hh]) * sinv[hh];
        }
        __syncthreads();
        int k = 0;
        for (; k + 3 < ne; k += 4) {
            int s0 = s_src[k],     s1 = s_src[k + 1];
            int s2 = s_src[k + 2], s3 = s_src[k + 3];
            float w0 = s_w[(k << 1) + myh],       w1 = s_w[((k + 1) << 1) + myh];
            float w2 = s_w[((k + 2) << 1) + myh], w3 = s_w[((k + 3) << 1) + myh];
            unsigned short v0 = h[(size_t)s0 * D2 + t];
            unsigned short v1 = h[(size_t)s1 * D2 + t];
            unsigned short v2 = h[(size_t)s2 * D2 + t];
            unsigned short v3 = h[(size_t)s3 * D2 + t];
            a0 += w0 * bf2f(v0); a1 += w1 * bf2f(v1);
            a2 += w2 * bf2f(v2); a3 += w3 * bf2f(v3);
        }
        for (; k < ne; k++) {
            a0 += s_w[(k << 1) + myh] * bf2f(h[(size_t)s_src[k] * D2 + t]);
        }
        __syncthreads();
    }
    red[t] = (a0 + a1) + (a2 + a3);
    __syncthreads();
    if (t < 128) {
        float v = (red[t] + red[t + 128]) * 0.5f + bias[t];
        out[(size_t)d * OUT2 + t] = elu1(v);
    }
}

// ---------------- pooling: per-graph sum of h2out (batch is SORTED) ----------------

__global__ __launch_bounds__(256) void pool_kernel(const float* __restrict__ h2,
                                                   const int* __restrict__ batch,
                                                   float* __restrict__ pooled) {
    int c = threadIdx.x & 127;
    int half = threadIdx.x >> 7;
    int n0 = blockIdx.x * 256 + half;
    int nend = blockIdx.x * 256 + 256;
    float acc = 0.f;
    int curg = batch[n0];
    for (int n = n0; n < nend; n += 2) {
        int g = batch[n];
        if (g != curg) {
            atomicAdd(&pooled[curg * OUT2 + c], acc);
            acc = 0.f; curg = g;
        }
        acc += h2[(size_t)n * OUT2 + c];
    }
    atomicAdd(&pooled[curg * OUT2 + c], acc);
}

// ---------------- per-graph head: proj + LN + risk MLP ----------------

__global__ __launch_bounds__(256) void final_kernel(const float* __restrict__ pooled_sum,
                                                    const int* __restrict__ n_g_i,
                                                    const int* __restrict__ e_cnt,
                                                    const float* __restrict__ projW,
                                                    const float* __restrict__ projb,
                                                    const float* __restrict__ lng,
                                                    const float* __restrict__ lnb,
                                                    const float* __restrict__ rhW1,
                                                    const float* __restrict__ rhb1,
                                                    const float* __restrict__ rhW2,
                                                    const float* __restrict__ rhb2,
                                                    float* __restrict__ out_se,
                                                    float* __restrict__ out_risk) {
    int b = blockIdx.x;
    int t = threadIdx.x;
    __shared__ float pooled[OUT2];
    __shared__ float pe[768];
    __shared__ float red[256];
    __shared__ float hid[32];
    __shared__ float stat_mu, stat_inv;

    float ng = (float)n_g_i[b];
    if (t < OUT2) pooled[t] = pooled_sum[b * OUT2 + t] / fmaxf(ng, 1.0f);
    __syncthreads();

    for (int j = t; j < 768; j += 256) {
        const float* wr = projW + (size_t)j * OUT2;
        float s = projb[j];
        for (int c = 0; c < OUT2; c++) s += pooled[c] * wr[c];
        pe[j] = s;
    }
    __syncthreads();

    float ls = 0.f, lq = 0.f;
    for (int j = t; j < 768; j += 256) { float v = pe[j]; ls += v; lq += v * v; }
    red[t] = ls;
    __syncthreads();
    for (int off = 128; off; off >>= 1) { if (t < off) red[t] += red[t + off]; __syncthreads(); }
    float tot = red[0];
    __syncthreads();
    red[t] = lq;
    __syncthreads();
    for (int off = 128; off; off >>= 1) { if (t < off) red[t] += red[t + off]; __syncthreads(); }
    float totq = red[0];
    if (t == 0) {
        float mu = tot / 768.f;
        float var = totq / 768.f - mu * mu;
        stat_mu = mu;
        stat_inv = 1.f / sqrtf(var + 1e-5f);
    }
    __syncthreads();
    float mu = stat_mu, inv = stat_inv;
    for (int j = t; j < 768; j += 256)
        out_se[(size_t)b * 768 + j] = (pe[j] - mu) * inv * lng[j] + lnb[j];

    float s0 = (float)e_cnt[b] / (ng + 1e-6f);
    float s1 = logf(ng + 1.0f);
    if (t < 32) {
        const float* wr = rhW1 + t * (OUT2 + 2);
        float s = rhb1[t];
        for (int c = 0; c < OUT2; c++) s += pooled[c] * wr[c];
        s += s0 * wr[OUT2] + s1 * wr[OUT2 + 1];
        hid[t] = fmaxf(s, 0.f);
    }
    __syncthreads();
    if (t == 0) {
        float s = rhb2[0];
        for (int k = 0; k < 32; k++) s += hid[k] * rhW2[k];
        out_risk[b] = 1.f / (1.f + __expf(-s));
    }
}

// ---------------- launch ----------------

extern "C" void kernel_launch(void* const* d_in, const int* in_sizes, int n_in,
                              void* d_out, int out_size, void* d_ws, size_t ws_size,
                              hipStream_t stream) {
    const float* x     = (const float*)d_in[0];
    const int*   ei    = (const int*)  d_in[1];
    const int*   batch = (const int*)  d_in[2];
    const float* W1    = (const float*)d_in[3];
    const float* a_s1  = (const float*)d_in[4];
    const float* a_d1  = (const float*)d_in[5];
    const float* b1    = (const float*)d_in[6];
    const float* W2    = (const float*)d_in[7];
    const float* a_s2  = (const float*)d_in[8];
    const float* a_d2  = (const float*)d_in[9];
    const float* b2    = (const float*)d_in[10];
    const float* projW = (const float*)d_in[11];
    const float* projb = (const float*)d_in[12];
    const float* lng   = (const float*)d_in[13];
    const float* lnb   = (const float*)d_in[14];
    const float* rhW1  = (const float*)d_in[15];
    const float* rhb1  = (const float*)d_in[16];
    const float* rhW2  = (const float*)d_in[17];
    const float* rhb2  = (const float*)d_in[18];

    char* ws = (char*)d_ws;
    size_t off = 0;
    auto alloc = [&](size_t bytes) -> void* {
        void* p = ws + off;
        off += (bytes + 255) & ~(size_t)255;
        return p;
    };

    unsigned short* regionA = (unsigned short*)alloc((size_t)2 * NN * D1 * 2);
    unsigned short* x_hi = regionA;
    unsigned short* x_lo = regionA + (size_t)NN * IN_F;
    unsigned short* h1hi = regionA;
    unsigned short* h1lo = regionA + (size_t)NN * D1;

    unsigned short* h1bf = (unsigned short*)alloc((size_t)NN * D1 * 2);
    unsigned short* h2bf = (unsigned short*)alloc((size_t)NN * D2 * 2);
    unsigned short* W1hi = (unsigned short*)alloc((size_t)D1 * IN_F * 2);
    unsigned short* W2hi = (unsigned short*)alloc((size_t)D2 * D1 * 2);
    unsigned short* W2lo = (unsigned short*)alloc((size_t)D2 * D1 * 2);
    float* als1   = (float*)alloc((size_t)NN * H1 * 4);
    float* ald1   = (float*)alloc((size_t)NN * H1 * 4);
    float* als2   = (float*)alloc((size_t)NN * H2 * 4);
    float* ald2   = (float*)alloc((size_t)NN * H2 * 4);
    int*   row_ptr= (int*)  alloc((size_t)(NN + 1) * 4);
    int*   colidx = (int*)  alloc((size_t)ET * 4);
    size_t zoff = off;
    int*   deg    = (int*)  alloc((size_t)NN * 4);
    int*   cursor = (int*)  alloc((size_t)NN * 4);
    int*   n_g    = (int*)  alloc((size_t)NB * 4);
    int*   e_cnt  = (int*)  alloc((size_t)NB * 4);
    float* pooled = (float*)alloc((size_t)NB * OUT2 * 4);
    size_t zbytes = off - zoff;

    float* out_se   = (float*)d_out;
    float* h2out    = out_se + NB * 768;
    float* out_risk = h2out + (size_t)NN * OUT2;

    hipMemsetAsync(ws + zoff, 0, zbytes, stream);

    hist_kernel<<<(EE + 255) / 256, 256, 0, stream>>>(ei, batch, deg, n_g, e_cnt);
    scan_kernel<<<1, 1024, 0, stream>>>(deg, row_ptr);
    scatter_kernel<<<(ET + 255) / 256, 256, 0, stream>>>(ei, row_ptr, cursor, colidx);

    split_kernel<<<((NN * IN_F / 4) + 255) / 256, 256, 0, stream>>>(x, x_hi, x_lo, NN * IN_F / 4);
    tobf_kernel<<<((D1 * IN_F / 4) + 255) / 256, 256, 0, stream>>>(W1, W1hi, D1 * IN_F / 4);
    split_kernel<<<((D2 * D1 / 4) + 255) / 256, 256, 0, stream>>>(W2, W2hi, W2lo, D2 * D1 / 4);

    gemm_mfma<2><<<(NN / BM) * (D1 / BN), 256, 0, stream>>>(x_hi, x_lo, W1hi, W1hi, h1bf, NN, D1, IN_F);
    al_kernel<H1, HID1><<<NN, H1 * 64, 0, stream>>>(h1bf, a_s1, a_d1, als1, ald1);
    agg1_kernel<<<NN, 256, 0, stream>>>(h1bf, als1, ald1, row_ptr, colidx, b1, h1hi, h1lo);

    gemm_mfma<3><<<(NN / BM) * (D2 / BN), 256, 0, stream>>>(h1hi, h1lo, W2hi, W2lo, h2bf, NN, D2, D1);
    al_kernel<H2, OUT2><<<NN, H2 * 64, 0, stream>>>(h2bf, a_s2, a_d2, als2, ald2);
    agg2_kernel<<<NN, 256, 0, stream>>>(h2bf, als2, ald2, row_ptr, colidx, b2, h2out);

    pool_kernel<<<NN / 256, 256, 0, stream>>>(h2out, batch, pooled);

    final_kernel<<<NB, 256, 0, stream>>>(pooled, n_g, e_cnt, projW, projb, lng, lnb,
                                         rhW1, rhb1, rhW2, rhb2, out_se, out_risk);
}